// Round 2
// baseline (2840.218 us; speedup 1.0000x reference)
//
#include <hip/hip_runtime.h>

// ---------------------------------------------------------------------------
// GCN 2-layer + FC head, fp32.
//   s = rsqrt(1 + indeg)           (self-loops)
//   L1: h = (x @ W1) * s[row]  ; agg = h + scatter_add(h[src] -> dst)
//       h1 = relu(s[row]*agg + b1)                      [N,256]
//   L2: same with W2 -> [N,128]
//   out = relu(...) @ Wfc + bfc                         [N,6]
// Edge indices arrive as int32 (harness stages integer inputs as int32).
// ---------------------------------------------------------------------------

__global__ void deg_init_kernel(float* __restrict__ deg, int n) {
    int i = blockIdx.x * blockDim.x + threadIdx.x;
    if (i < n) deg[i] = 1.0f;  // self-loop
}

__global__ void deg_count_kernel(const int* __restrict__ dst,
                                 float* __restrict__ deg, int e) {
    for (int i = blockIdx.x * blockDim.x + threadIdx.x; i < e;
         i += gridDim.x * blockDim.x)
        atomicAdd(&deg[dst[i]], 1.0f);
}

__global__ void deg_rsqrt_kernel(float* __restrict__ deg, int n) {
    int i = blockIdx.x * blockDim.x + threadIdx.x;
    if (i < n) deg[i] = rsqrtf(deg[i]);
}

// C[M,Nc] = (A[M,K] @ B[K,Nc]) * rowscale[m]    (row-major everywhere)
// Requires K % 16 == 0, Nc % 64 == 0. Block 256 thr, 64x64 tile, 4x4/thread.
__global__ void gemm_rowscale_kernel(const float* __restrict__ A,
                                     const float* __restrict__ B,
                                     float* __restrict__ C,
                                     const float* __restrict__ rowscale,
                                     int M, int K, int Nc) {
    __shared__ float As[64][17];
    __shared__ float Bs[16][65];
    const int tid = threadIdx.x;
    const int tr = tid >> 4;        // 0..15
    const int tc = tid & 15;        // 0..15
    const int row0 = blockIdx.y * 64;
    const int col0 = blockIdx.x * 64;

    float acc[4][4] = {};
    for (int k0 = 0; k0 < K; k0 += 16) {
        #pragma unroll
        for (int i = 0; i < 4; i++) {      // 1024 = 64x16 A elements
            int idx = tid + i * 256;
            int r = idx >> 4, c = idx & 15;
            int gr = row0 + r;
            As[r][c] = (gr < M) ? A[(long long)gr * K + k0 + c] : 0.0f;
        }
        #pragma unroll
        for (int i = 0; i < 4; i++) {      // 1024 = 16x64 B elements
            int idx = tid + i * 256;
            int r = idx >> 6, c = idx & 63;
            Bs[r][c] = B[(long long)(k0 + r) * Nc + col0 + c];
        }
        __syncthreads();
        #pragma unroll
        for (int kk = 0; kk < 16; kk++) {
            float a[4], b[4];
            #pragma unroll
            for (int i = 0; i < 4; i++) a[i] = As[tr * 4 + i][kk];
            #pragma unroll
            for (int j = 0; j < 4; j++) b[j] = Bs[kk][tc * 4 + j];
            #pragma unroll
            for (int i = 0; i < 4; i++)
                #pragma unroll
                for (int j = 0; j < 4; j++) acc[i][j] += a[i] * b[j];
        }
        __syncthreads();
    }
    #pragma unroll
    for (int i = 0; i < 4; i++) {
        int gr = row0 + tr * 4 + i;
        if (gr >= M) continue;
        float s = rowscale[gr];
        #pragma unroll
        for (int j = 0; j < 4; j++)
            C[(long long)gr * Nc + col0 + tc * 4 + j] = acc[i][j] * s;
    }
}

// agg[dst] += h[src], rows of C floats (C = 4*c4). c4 lanes per edge row.
__global__ void scatter_add_kernel(const float4* __restrict__ h,
                                   float* __restrict__ agg,
                                   const int* __restrict__ src,
                                   const int* __restrict__ dst,
                                   int E, int c4) {
    int lane = threadIdx.x & 63;
    int gwave = (blockIdx.x * blockDim.x + threadIdx.x) >> 6;
    int epw = 64 / c4;               // edges per wave (1 for C=256, 2 for C=128)
    int sub = lane / c4;
    int sl  = lane % c4;
    long long e = (long long)gwave * epw + sub;
    if (e >= E) return;
    int s = src[e];
    int d = dst[e];
    float4 v = h[(long long)s * c4 + sl];
    float* ap = agg + ((long long)d * c4 + sl) * 4;
    atomicAdd(ap + 0, v.x);
    atomicAdd(ap + 1, v.y);
    atomicAdd(ap + 2, v.z);
    atomicAdd(ap + 3, v.w);
}

// buf[i,c] = relu(s[i]*buf[i,c] + bias[c]), vectorized float4, in place.
__global__ void post_bias_relu_kernel(float4* __restrict__ buf,
                                      const float* __restrict__ disq,
                                      const float* __restrict__ bias,
                                      int total4, int c4) {
    int i = blockIdx.x * blockDim.x + threadIdx.x;
    if (i >= total4) return;
    int row = i / c4;
    int col = (i % c4) * 4;
    float s = disq[row];
    float4 v = buf[i];
    v.x = fmaxf(fmaf(v.x, s, bias[col + 0]), 0.0f);
    v.y = fmaxf(fmaf(v.y, s, bias[col + 1]), 0.0f);
    v.z = fmaxf(fmaf(v.z, s, bias[col + 2]), 0.0f);
    v.w = fmaxf(fmaf(v.w, s, bias[col + 3]), 0.0f);
    buf[i] = v;
}

// out[n,0:6] = relu(s[n]*agg2[n,:] + b2) @ Wfc + bfc ; one wave per node.
__global__ void final_fc_kernel(const float* __restrict__ agg,
                                const float* __restrict__ disq,
                                const float* __restrict__ b2,
                                const float* __restrict__ Wfc,   // [128,6]
                                const float* __restrict__ bfc,   // [6]
                                float* __restrict__ out, int n) {
    __shared__ float wf[128 * 6];
    for (int i = threadIdx.x; i < 128 * 6; i += blockDim.x) wf[i] = Wfc[i];
    __syncthreads();
    int lane = threadIdx.x & 63;
    int wave = (blockIdx.x * blockDim.x + threadIdx.x) >> 6;
    int nwaves = (gridDim.x * blockDim.x) >> 6;
    for (int node = wave; node < n; node += nwaves) {
        float s = disq[node];
        float h0 = fmaxf(fmaf(agg[(long long)node * 128 + lane], s, b2[lane]), 0.0f);
        float h1 = fmaxf(fmaf(agg[(long long)node * 128 + 64 + lane], s, b2[64 + lane]), 0.0f);
        float acc[6];
        #pragma unroll
        for (int j = 0; j < 6; j++)
            acc[j] = h0 * wf[lane * 6 + j] + h1 * wf[(64 + lane) * 6 + j];
        #pragma unroll
        for (int off = 32; off >= 1; off >>= 1)
            #pragma unroll
            for (int j = 0; j < 6; j++) acc[j] += __shfl_down(acc[j], off);
        if (lane == 0) {
            #pragma unroll
            for (int j = 0; j < 6; j++) out[(long long)node * 6 + j] = acc[j] + bfc[j];
        }
    }
}

extern "C" void kernel_launch(void* const* d_in, const int* in_sizes, int n_in,
                              void* d_out, int out_size, void* d_ws, size_t ws_size,
                              hipStream_t stream) {
    const float* x   = (const float*)d_in[0];
    const float* W1  = (const float*)d_in[1];
    const float* b1  = (const float*)d_in[2];
    const float* W2  = (const float*)d_in[3];
    const float* b2  = (const float*)d_in[4];
    const float* Wfc = (const float*)d_in[5];
    const float* bfc = (const float*)d_in[6];
    const int* edges = (const int*)d_in[7];   // int inputs staged as int32

    const int N = in_sizes[0] / 128;       // 50000
    const int E = in_sizes[7] / 2;         // 500000
    const int* e_src = edges;
    const int* e_dst = edges + E;

    // workspace layout (floats)
    float* disq = (float*)d_ws;                         // N (padded)
    float* bufA = disq + ((N + 255) & ~255);            // N*256
    float* bufB = bufA + (long long)N * 256;            // N*256
    (void)ws_size; (void)n_in;

    float* out = (float*)d_out; (void)out_size;

    // --- degrees ---
    deg_init_kernel<<<(N + 255) / 256, 256, 0, stream>>>(disq, N);
    deg_count_kernel<<<2048, 256, 0, stream>>>(e_dst, disq, E);
    deg_rsqrt_kernel<<<(N + 255) / 256, 256, 0, stream>>>(disq, N);

    // --- layer 1: h = (x@W1)*s  -> bufA [N,256] ---
    {
        dim3 g(256 / 64, (N + 63) / 64);
        gemm_rowscale_kernel<<<g, 256, 0, stream>>>(x, W1, bufA, disq, N, 128, 256);
    }
    // self-loop init + scatter
    hipMemcpyAsync(bufB, bufA, (size_t)N * 256 * sizeof(float),
                   hipMemcpyDeviceToDevice, stream);
    {
        int c4 = 64;                       // 256 channels, 1 edge per wave
        long long waves = E;
        int blocks = (int)((waves + 3) / 4);
        scatter_add_kernel<<<blocks, 256, 0, stream>>>((const float4*)bufA, bufB,
                                                       e_src, e_dst, E, c4);
    }
    {
        int total4 = N * 64;
        post_bias_relu_kernel<<<(total4 + 255) / 256, 256, 0, stream>>>(
            (float4*)bufB, disq, b1, total4, 64);
    }

    // --- layer 2: h2 = (h1@W2)*s -> bufA [N,128] ---
    {
        dim3 g(128 / 64, (N + 63) / 64);
        gemm_rowscale_kernel<<<g, 256, 0, stream>>>(bufB, W2, bufA, disq, N, 256, 128);
    }
    hipMemcpyAsync(bufB, bufA, (size_t)N * 128 * sizeof(float),
                   hipMemcpyDeviceToDevice, stream);
    {
        int c4 = 32;                       // 128 channels, 2 edges/wave
        long long waves = (E + 1) / 2;
        int blocks = (int)((waves + 3) / 4);
        scatter_add_kernel<<<blocks, 256, 0, stream>>>((const float4*)bufA, bufB,
                                                       e_src, e_dst, E, c4);
    }

    // --- fused post + FC head ---
    final_fc_kernel<<<1024, 256, 0, stream>>>(bufB, disq, b2, Wfc, bfc, out, N);
}

// Round 3
// 529.356 us; speedup vs baseline: 5.3654x; 5.3654x over previous
//
#include <hip/hip_runtime.h>

// ---------------------------------------------------------------------------
// GCN 2-layer + FC head, fp32, CSR-gather aggregation (no fp32 atomics).
//   s = rsqrt(1 + indeg)
//   h  = (x @ W) * s[row]                     (pre-scale in GEMM epilogue)
//   a  = h[i] + sum_{j->i} h[j]               (CSR gather, self-loop fused)
//   h' = relu(s[i]*a + b)                     (fused in gather epilogue)
// CSR built on device every launch: count -> exclusive scan -> cursor fill.
// ---------------------------------------------------------------------------

__global__ void count_kernel(const int* __restrict__ dst, int* __restrict__ cnt,
                             int e) {
    for (int i = blockIdx.x * blockDim.x + threadIdx.x; i < e;
         i += gridDim.x * blockDim.x)
        atomicAdd(&cnt[dst[i]], 1);
}

__global__ void disq_kernel(const int* __restrict__ cnt, float* __restrict__ disq,
                            int n) {
    int i = blockIdx.x * blockDim.x + threadIdx.x;
    if (i < n) disq[i] = rsqrtf(1.0f + (float)cnt[i]);
}

// Single-block exclusive scan of cnt[0..n) -> row_ptr, cursor. 1024 threads.
__global__ void exscan_kernel(const int* __restrict__ cnt, int* __restrict__ row_ptr,
                              int* __restrict__ cursor, int n) {
    __shared__ int lds[1024];
    __shared__ int carry_s;
    if (threadIdx.x == 0) carry_s = 0;
    __syncthreads();
    for (int base = 0; base < n; base += 1024) {
        int i = base + (int)threadIdx.x;
        int v = (i < n) ? cnt[i] : 0;
        int c = carry_s;
        lds[threadIdx.x] = v;
        __syncthreads();
        for (int off = 1; off < 1024; off <<= 1) {
            int t = (threadIdx.x >= (unsigned)off) ? lds[threadIdx.x - off] : 0;
            __syncthreads();
            lds[threadIdx.x] += t;
            __syncthreads();
        }
        int excl = c + lds[threadIdx.x] - v;
        if (i < n) { row_ptr[i] = excl; cursor[i] = excl; }
        int total = lds[1023];
        __syncthreads();
        if (threadIdx.x == 0) carry_s = c + total;
        __syncthreads();
    }
    if (threadIdx.x == 0) row_ptr[n] = carry_s;
}

__global__ void csr_fill_kernel(const int* __restrict__ src, const int* __restrict__ dst,
                                int* __restrict__ cursor, int* __restrict__ esorted,
                                int e) {
    for (int i = blockIdx.x * blockDim.x + threadIdx.x; i < e;
         i += gridDim.x * blockDim.x) {
        int d = dst[i];
        int pos = atomicAdd(&cursor[d], 1);
        esorted[pos] = src[i];
    }
}

// C[M,Nc] = (A[M,K] @ B[K,Nc]) * rowscale[m]. 64x64 tile, 4x4/thread, 256 thr.
__global__ void gemm_rowscale_kernel(const float* __restrict__ A,
                                     const float* __restrict__ B,
                                     float* __restrict__ C,
                                     const float* __restrict__ rowscale,
                                     int M, int K, int Nc) {
    __shared__ float As[64][17];
    __shared__ float Bs[16][65];
    const int tid = threadIdx.x;
    const int tr = tid >> 4;
    const int tc = tid & 15;
    const int row0 = blockIdx.y * 64;
    const int col0 = blockIdx.x * 64;

    float acc[4][4] = {};
    for (int k0 = 0; k0 < K; k0 += 16) {
        #pragma unroll
        for (int i = 0; i < 4; i++) {
            int idx = tid + i * 256;
            int r = idx >> 4, c = idx & 15;
            int gr = row0 + r;
            As[r][c] = (gr < M) ? A[(long long)gr * K + k0 + c] : 0.0f;
        }
        #pragma unroll
        for (int i = 0; i < 4; i++) {
            int idx = tid + i * 256;
            int r = idx >> 6, c = idx & 63;
            Bs[r][c] = B[(long long)(k0 + r) * Nc + col0 + c];
        }
        __syncthreads();
        #pragma unroll
        for (int kk = 0; kk < 16; kk++) {
            float a[4], b[4];
            #pragma unroll
            for (int i = 0; i < 4; i++) a[i] = As[tr * 4 + i][kk];
            #pragma unroll
            for (int j = 0; j < 4; j++) b[j] = Bs[kk][tc * 4 + j];
            #pragma unroll
            for (int i = 0; i < 4; i++)
                #pragma unroll
                for (int j = 0; j < 4; j++) acc[i][j] += a[i] * b[j];
        }
        __syncthreads();
    }
    #pragma unroll
    for (int i = 0; i < 4; i++) {
        int gr = row0 + tr * 4 + i;
        if (gr >= M) continue;
        float s = rowscale[gr];
        #pragma unroll
        for (int j = 0; j < 4; j++)
            C[(long long)gr * Nc + col0 + tc * 4 + j] = acc[i][j] * s;
    }
}

// out[node] = relu(disq[node] * (h[node] + sum_{e in CSR[node]} h[src_e]) + bias)
// Row = c4 float4s. c4=64 -> 1 node/wave; c4=32 -> 2 nodes/wave.
__global__ void gather_relu_kernel(const float4* __restrict__ h,
                                   float4* __restrict__ out,
                                   const int* __restrict__ row_ptr,
                                   const int* __restrict__ esorted,
                                   const float* __restrict__ disq,
                                   const float* __restrict__ bias,
                                   int n, int c4) {
    int lane = threadIdx.x & 63;
    int wave = (blockIdx.x * blockDim.x + threadIdx.x) >> 6;
    int epw = 64 / c4;
    int sub = lane / c4;
    int sl = lane - sub * c4;
    long long node = (long long)wave * epw + sub;
    if (node >= n) return;
    int beg = row_ptr[node], end = row_ptr[node + 1];
    float4 acc = h[node * c4 + sl];               // self-loop term
    for (int e = beg; e < end; e++) {
        int s = esorted[e];
        float4 v = h[(long long)s * c4 + sl];
        acc.x += v.x; acc.y += v.y; acc.z += v.z; acc.w += v.w;
    }
    float sc = disq[node];
    int col = sl * 4;
    float4 r;
    r.x = fmaxf(fmaf(acc.x, sc, bias[col + 0]), 0.0f);
    r.y = fmaxf(fmaf(acc.y, sc, bias[col + 1]), 0.0f);
    r.z = fmaxf(fmaf(acc.z, sc, bias[col + 2]), 0.0f);
    r.w = fmaxf(fmaf(acc.w, sc, bias[col + 3]), 0.0f);
    out[node * c4 + sl] = r;
}

// out[n,0:6] = h2[n,:] @ Wfc + bfc ; one wave per node (h2 already relu'd).
__global__ void final_fc_kernel(const float* __restrict__ h,
                                const float* __restrict__ Wfc,   // [128,6]
                                const float* __restrict__ bfc,   // [6]
                                float* __restrict__ out, int n) {
    __shared__ float wf[128 * 6];
    for (int i = threadIdx.x; i < 128 * 6; i += blockDim.x) wf[i] = Wfc[i];
    __syncthreads();
    int lane = threadIdx.x & 63;
    int wave = (blockIdx.x * blockDim.x + threadIdx.x) >> 6;
    int nwaves = (gridDim.x * blockDim.x) >> 6;
    for (int node = wave; node < n; node += nwaves) {
        float h0 = h[(long long)node * 128 + lane];
        float h1 = h[(long long)node * 128 + 64 + lane];
        float acc[6];
        #pragma unroll
        for (int j = 0; j < 6; j++)
            acc[j] = h0 * wf[lane * 6 + j] + h1 * wf[(64 + lane) * 6 + j];
        #pragma unroll
        for (int off = 32; off >= 1; off >>= 1)
            #pragma unroll
            for (int j = 0; j < 6; j++) acc[j] += __shfl_down(acc[j], off);
        if (lane == 0) {
            #pragma unroll
            for (int j = 0; j < 6; j++)
                out[(long long)node * 6 + j] = acc[j] + bfc[j];
        }
    }
}

extern "C" void kernel_launch(void* const* d_in, const int* in_sizes, int n_in,
                              void* d_out, int out_size, void* d_ws, size_t ws_size,
                              hipStream_t stream) {
    const float* x   = (const float*)d_in[0];
    const float* W1  = (const float*)d_in[1];
    const float* b1  = (const float*)d_in[2];
    const float* W2  = (const float*)d_in[3];
    const float* b2  = (const float*)d_in[4];
    const float* Wfc = (const float*)d_in[5];
    const float* bfc = (const float*)d_in[6];
    const int* edges = (const int*)d_in[7];   // int inputs staged as int32

    const int N = in_sizes[0] / 128;       // 50000
    const int E = in_sizes[7] / 2;         // 500000
    const int* e_src = edges;
    const int* e_dst = edges + E;

    // workspace layout (256B-aligned chunks)
    char* ws = (char*)d_ws;
    size_t off = 0;
    auto alloc = [&](size_t bytes) {
        void* p = ws + off;
        off += (bytes + 255) & ~(size_t)255;
        return p;
    };
    float* disq    = (float*)alloc((size_t)N * 4);
    int*   cnt     = (int*)  alloc((size_t)N * 4);
    int*   row_ptr = (int*)  alloc((size_t)(N + 1) * 4);
    int*   cursor  = (int*)  alloc((size_t)N * 4);
    int*   esorted = (int*)  alloc((size_t)E * 4);
    float* bufA    = (float*)alloc((size_t)N * 256 * 4);
    float* bufB    = (float*)alloc((size_t)N * 256 * 4);
    (void)ws_size; (void)n_in;

    float* out = (float*)d_out; (void)out_size;

    // --- CSR build + degree scales ---
    hipMemsetAsync(cnt, 0, (size_t)N * sizeof(int), stream);
    count_kernel<<<2048, 256, 0, stream>>>(e_dst, cnt, E);
    disq_kernel<<<(N + 255) / 256, 256, 0, stream>>>(cnt, disq, N);
    exscan_kernel<<<1, 1024, 0, stream>>>(cnt, row_ptr, cursor, N);
    csr_fill_kernel<<<2048, 256, 0, stream>>>(e_src, e_dst, cursor, esorted, E);

    // --- layer 1: h = (x@W1)*s -> bufA [N,256]; gather+relu -> bufB ---
    {
        dim3 g(256 / 64, (N + 63) / 64);
        gemm_rowscale_kernel<<<g, 256, 0, stream>>>(x, W1, bufA, disq, N, 128, 256);
    }
    {
        int waves = N;                      // c4=64: 1 node/wave
        int blocks = (waves + 3) / 4;
        gather_relu_kernel<<<blocks, 256, 0, stream>>>(
            (const float4*)bufA, (float4*)bufB, row_ptr, esorted, disq, b1, N, 64);
    }

    // --- layer 2: h2 = (h1@W2)*s -> bufA [N,128]; gather+relu -> bufB ---
    {
        dim3 g(128 / 64, (N + 63) / 64);
        gemm_rowscale_kernel<<<g, 256, 0, stream>>>(bufB, W2, bufA, disq, N, 256, 128);
    }
    {
        int waves = (N + 1) / 2;            // c4=32: 2 nodes/wave
        int blocks = (waves + 3) / 4;
        gather_relu_kernel<<<blocks, 256, 0, stream>>>(
            (const float4*)bufA, (float4*)bufB, row_ptr, esorted, disq, b2, N, 32);
    }

    // --- FC head ---
    final_fc_kernel<<<1024, 256, 0, stream>>>(bufB, Wfc, bfc, out, N);
}

// Round 4
// 363.423 us; speedup vs baseline: 7.8152x; 1.4566x over previous
//
#include <hip/hip_runtime.h>

// ---------------------------------------------------------------------------
// GCN 2-layer + FC head. CSR gather + f16 MFMA GEMMs; fp32 accumulation.
//   s = rsqrt(1 + indeg)
//   h  = f16((x @ W) * s[row])          (MFMA GEMM, epilogue row-scale)
//   a  = h[i] + sum_{j->i} h[j]         (CSR gather, fp32 acc)
//   h' = f16(relu(s[i]*a + b))
//   out = h2' @ Wfc + bfc               (fp32)
// ---------------------------------------------------------------------------

typedef _Float16 f16;
typedef __attribute__((ext_vector_type(8))) _Float16 f16x8;
typedef __attribute__((ext_vector_type(4))) float f32x4;

// ---------------- CSR build ----------------
__global__ void count_kernel(const int* __restrict__ dst, int* __restrict__ cnt,
                             int e) {
    for (int i = blockIdx.x * blockDim.x + threadIdx.x; i < e;
         i += gridDim.x * blockDim.x)
        atomicAdd(&cnt[dst[i]], 1);
}

__global__ void disq_kernel(const int* __restrict__ cnt, float* __restrict__ disq,
                            int n) {
    int i = blockIdx.x * blockDim.x + threadIdx.x;
    if (i < n) disq[i] = rsqrtf(1.0f + (float)cnt[i]);
}

__global__ void exscan_kernel(const int* __restrict__ cnt, int* __restrict__ row_ptr,
                              int* __restrict__ cursor, int n) {
    __shared__ int lds[1024];
    __shared__ int carry_s;
    if (threadIdx.x == 0) carry_s = 0;
    __syncthreads();
    for (int base = 0; base < n; base += 1024) {
        int i = base + (int)threadIdx.x;
        int v = (i < n) ? cnt[i] : 0;
        int c = carry_s;
        lds[threadIdx.x] = v;
        __syncthreads();
        for (int off = 1; off < 1024; off <<= 1) {
            int t = (threadIdx.x >= (unsigned)off) ? lds[threadIdx.x - off] : 0;
            __syncthreads();
            lds[threadIdx.x] += t;
            __syncthreads();
        }
        int excl = c + lds[threadIdx.x] - v;
        if (i < n) { row_ptr[i] = excl; cursor[i] = excl; }
        int total = lds[1023];
        __syncthreads();
        if (threadIdx.x == 0) carry_s = c + total;
        __syncthreads();
    }
    if (threadIdx.x == 0) row_ptr[n] = carry_s;
}

__global__ void csr_fill_kernel(const int* __restrict__ src, const int* __restrict__ dst,
                                int* __restrict__ cursor, int* __restrict__ esorted,
                                int e) {
    for (int i = blockIdx.x * blockDim.x + threadIdx.x; i < e;
         i += gridDim.x * blockDim.x) {
        int d = dst[i];
        int pos = atomicAdd(&cursor[d], 1);
        esorted[pos] = src[i];
    }
}

// ---------------- dtype conversion ----------------
__global__ void cvt_f32_f16_kernel(const float4* __restrict__ in,
                                   f16* __restrict__ out, long long n4) {
    long long i = blockIdx.x * (long long)blockDim.x + threadIdx.x;
    if (i >= n4) return;
    float4 v = in[i];
    union { f16 h[4]; short4 s; } u;
    u.h[0] = (f16)v.x; u.h[1] = (f16)v.y; u.h[2] = (f16)v.z; u.h[3] = (f16)v.w;
    *(short4*)(out + i * 4) = u.s;
}

// Wt[n][k] = (f16) W[k][n]
__global__ void cvt_wt_kernel(const float* __restrict__ W, f16* __restrict__ Wt,
                              int K, int Nc) {
    int i = blockIdx.x * blockDim.x + threadIdx.x;
    if (i >= K * Nc) return;
    int n = i / K, k = i - n * K;
    Wt[i] = (f16)W[(long long)k * Nc + n];
}

// ---------------- f16 MFMA GEMM ----------------
// C[M][Nc] = f16( (A[M][K] @ Bt[Nc][K]^T) * rowscale[m] )
// Block: 256 thr (4 waves, 2x2), tile 128x64, BK=64, mfma 16x16x32 f16.
__global__ __launch_bounds__(256)
void gemm_f16_kernel(const f16* __restrict__ A,
                     const f16* __restrict__ Bt,
                     f16* __restrict__ C,
                     const float* __restrict__ rowscale,
                     int M, int K, int Nc) {
    __shared__ __align__(16) char smem[(128 * 64 + 64 * 64) * 2]; // As 16KB + Bs 8KB
    char* As = smem;                 // [128 rows][64 f16] = 128B rows, swizzled
    char* Bs = smem + 128 * 64 * 2;  // [64 cols ][64 f16] = 128B rows, swizzled
    const int tid = threadIdx.x;
    const int lane = tid & 63;
    const int wid = tid >> 6;
    const int wr = wid >> 1;   // 0..1  -> 64-row half
    const int wc = wid & 1;    // 0..1  -> 32-col half
    const int row0 = blockIdx.y * 128;
    const int col0 = blockIdx.x * 64;

    f32x4 acc[4][2];
    #pragma unroll
    for (int mr = 0; mr < 4; mr++)
        #pragma unroll
        for (int nr = 0; nr < 2; nr++)
            acc[mr][nr] = (f32x4){0.f, 0.f, 0.f, 0.f};

    for (int k0 = 0; k0 < K; k0 += 64) {
        // stage A: 128x64 f16 = 1024 float4 slots, 4 per thread
        #pragma unroll
        for (int i = 0; i < 4; i++) {
            int flat = tid + i * 256;
            int r = flat >> 3, g = flat & 7;
            int gr = row0 + r;
            float4 v = {0.f, 0.f, 0.f, 0.f};
            if (gr < M) v = *(const float4*)(A + (long long)gr * K + k0 + g * 8);
            *(float4*)(As + r * 128 + ((g * 16) ^ ((r & 7) << 4))) = v;
        }
        // stage B: 64x64 f16 = 512 float4 slots, 2 per thread
        #pragma unroll
        for (int i = 0; i < 2; i++) {
            int flat = tid + i * 256;
            int nn = flat >> 3, g = flat & 7;
            float4 v = *(const float4*)(Bt + (long long)(col0 + nn) * K + k0 + g * 8);
            *(float4*)(Bs + nn * 128 + ((g * 16) ^ ((nn & 7) << 4))) = v;
        }
        __syncthreads();
        #pragma unroll
        for (int ks = 0; ks < 2; ks++) {
            const int kb = (ks * 32 + ((lane >> 4) * 8)) * 2;  // byte-in-row
            f16x8 af[4], bf[2];
            #pragma unroll
            for (int mr = 0; mr < 4; mr++) {
                int r = wr * 64 + mr * 16 + (lane & 15);
                af[mr] = *(const f16x8*)(As + r * 128 + (kb ^ ((r & 7) << 4)));
            }
            #pragma unroll
            for (int nr = 0; nr < 2; nr++) {
                int c = wc * 32 + nr * 16 + (lane & 15);
                bf[nr] = *(const f16x8*)(Bs + c * 128 + (kb ^ ((c & 7) << 4)));
            }
            #pragma unroll
            for (int mr = 0; mr < 4; mr++)
                #pragma unroll
                for (int nr = 0; nr < 2; nr++)
                    acc[mr][nr] = __builtin_amdgcn_mfma_f32_16x16x32_f16(
                        af[mr], bf[nr], acc[mr][nr], 0, 0, 0);
        }
        __syncthreads();
    }
    // epilogue: C/D map col=lane&15, row=(lane>>4)*4+reg  [m89-verified]
    #pragma unroll
    for (int mr = 0; mr < 4; mr++) {
        #pragma unroll
        for (int reg = 0; reg < 4; reg++) {
            int row = row0 + wr * 64 + mr * 16 + (lane >> 4) * 4 + reg;
            if (row < M) {
                float s = rowscale[row];
                int col = col0 + wc * 32 + (lane & 15);
                #pragma unroll
                for (int nr = 0; nr < 2; nr++)
                    C[(long long)row * Nc + col + nr * 16] =
                        (f16)(acc[mr][nr][reg] * s);
            }
        }
    }
}

// ---------------- CSR gather + bias + relu (f16 rows) ----------------
// out[node] = f16(relu(disq[node]*(h[node] + sum h[src]) + bias))
// Row = c8 float4s (8 f16 each). c8=32 -> 2 nodes/wave, c8=16 -> 4.
__global__ void gather_relu_f16_kernel(const float4* __restrict__ h,
                                       float4* __restrict__ out,
                                       const int* __restrict__ row_ptr,
                                       const int* __restrict__ esorted,
                                       const float* __restrict__ disq,
                                       const float* __restrict__ bias,
                                       int n, int c8) {
    int lane = threadIdx.x & 63;
    long long wave = (blockIdx.x * (long long)blockDim.x + threadIdx.x) >> 6;
    int epw = 64 / c8;
    int sub = lane / c8;
    int sl = lane - sub * c8;
    long long node = wave * epw + sub;
    if (node >= n) return;
    int beg = row_ptr[node], end = row_ptr[node + 1];
    float acc[8];
    {
        float4 v = h[node * c8 + sl];
        const f16* hp = (const f16*)&v;
        #pragma unroll
        for (int j = 0; j < 8; j++) acc[j] = (float)hp[j];
    }
    for (int e = beg; e < end; e++) {
        int s = esorted[e];
        float4 v = h[(long long)s * c8 + sl];
        const f16* hp = (const f16*)&v;
        #pragma unroll
        for (int j = 0; j < 8; j++) acc[j] += (float)hp[j];
    }
    float sc = disq[node];
    const float4* b4 = (const float4*)(bias + sl * 8);
    float4 b0 = b4[0], b1 = b4[1];
    float bb[8] = {b0.x, b0.y, b0.z, b0.w, b1.x, b1.y, b1.z, b1.w};
    union { float4 f4; f16 hh[8]; } o;
    #pragma unroll
    for (int j = 0; j < 8; j++)
        o.hh[j] = (f16)fmaxf(fmaf(acc[j], sc, bb[j]), 0.0f);
    out[node * c8 + sl] = o.f4;
}

// ---------------- FC head ----------------
__global__ void final_fc_kernel(const f16* __restrict__ h,   // [N][128] f16
                                const float* __restrict__ Wfc,  // [128,6]
                                const float* __restrict__ bfc,
                                float* __restrict__ out, int n) {
    __shared__ float wf[128 * 6];
    for (int i = threadIdx.x; i < 128 * 6; i += blockDim.x) wf[i] = Wfc[i];
    __syncthreads();
    int lane = threadIdx.x & 63;
    int wave = (blockIdx.x * blockDim.x + threadIdx.x) >> 6;
    int nwaves = (gridDim.x * blockDim.x) >> 6;
    for (int node = wave; node < n; node += nwaves) {
        const f16* hp = h + (long long)node * 128 + lane * 2;
        float v0 = (float)hp[0], v1 = (float)hp[1];
        float acc[6];
        #pragma unroll
        for (int j = 0; j < 6; j++)
            acc[j] = v0 * wf[(2 * lane) * 6 + j] + v1 * wf[(2 * lane + 1) * 6 + j];
        #pragma unroll
        for (int off = 32; off >= 1; off >>= 1)
            #pragma unroll
            for (int j = 0; j < 6; j++) acc[j] += __shfl_down(acc[j], off);
        if (lane == 0) {
            #pragma unroll
            for (int j = 0; j < 6; j++)
                out[(long long)node * 6 + j] = acc[j] + bfc[j];
        }
    }
}

extern "C" void kernel_launch(void* const* d_in, const int* in_sizes, int n_in,
                              void* d_out, int out_size, void* d_ws, size_t ws_size,
                              hipStream_t stream) {
    const float* x   = (const float*)d_in[0];
    const float* W1  = (const float*)d_in[1];
    const float* b1  = (const float*)d_in[2];
    const float* W2  = (const float*)d_in[3];
    const float* b2  = (const float*)d_in[4];
    const float* Wfc = (const float*)d_in[5];
    const float* bfc = (const float*)d_in[6];
    const int* edges = (const int*)d_in[7];

    const int N = in_sizes[0] / 128;       // 50000
    const int E = in_sizes[7] / 2;         // 500000
    const int* e_src = edges;
    const int* e_dst = edges + E;

    char* ws = (char*)d_ws;
    size_t off = 0;
    auto alloc = [&](size_t bytes) {
        void* p = ws + off;
        off += (bytes + 255) & ~(size_t)255;
        return p;
    };
    float* disq    = (float*)alloc((size_t)N * 4);
    int*   cnt     = (int*)  alloc((size_t)N * 4);
    int*   row_ptr = (int*)  alloc((size_t)(N + 1) * 4);
    int*   cursor  = (int*)  alloc((size_t)N * 4);
    int*   esorted = (int*)  alloc((size_t)E * 4);
    f16*   x_h     = (f16*)  alloc((size_t)N * 128 * 2);
    f16*   wt1     = (f16*)  alloc((size_t)256 * 128 * 2);  // [256][128]
    f16*   wt2     = (f16*)  alloc((size_t)128 * 256 * 2);  // [128][256]
    f16*   hbuf    = (f16*)  alloc((size_t)N * 256 * 2);    // GEMM out (scaled)
    f16*   gbuf    = (f16*)  alloc((size_t)N * 256 * 2);    // gather out
    (void)ws_size; (void)n_in;

    float* out = (float*)d_out; (void)out_size;

    // --- CSR + degree scales ---
    hipMemsetAsync(cnt, 0, (size_t)N * sizeof(int), stream);
    count_kernel<<<2048, 256, 0, stream>>>(e_dst, cnt, E);
    disq_kernel<<<(N + 255) / 256, 256, 0, stream>>>(cnt, disq, N);
    exscan_kernel<<<1, 1024, 0, stream>>>(cnt, row_ptr, cursor, N);
    csr_fill_kernel<<<2048, 256, 0, stream>>>(e_src, e_dst, cursor, esorted, E);

    // --- conversions ---
    {
        long long n4 = (long long)N * 128 / 4;
        cvt_f32_f16_kernel<<<(int)((n4 + 255) / 256), 256, 0, stream>>>(
            (const float4*)x, x_h, n4);
    }
    cvt_wt_kernel<<<(128 * 256 + 255) / 256, 256, 0, stream>>>(W1, wt1, 128, 256);
    cvt_wt_kernel<<<(256 * 128 + 255) / 256, 256, 0, stream>>>(W2, wt2, 256, 128);

    // --- layer 1: h = (x@W1)*s -> hbuf [N,256] f16 ; gather -> gbuf ---
    {
        dim3 g(256 / 64, (N + 127) / 128);
        gemm_f16_kernel<<<g, 256, 0, stream>>>(x_h, wt1, hbuf, disq, N, 128, 256);
    }
    {
        long long waves = ((long long)N + 1) / 2;        // c8=32
        int blocks = (int)((waves + 3) / 4);
        gather_relu_f16_kernel<<<blocks, 256, 0, stream>>>(
            (const float4*)hbuf, (float4*)gbuf, row_ptr, esorted, disq, b1, N, 32);
    }

    // --- layer 2: h2 = (h1@W2)*s -> hbuf [N,128] f16 ; gather -> gbuf ---
    {
        dim3 g(128 / 64, (N + 127) / 128);
        gemm_f16_kernel<<<g, 256, 0, stream>>>(gbuf, wt2, hbuf, disq, N, 256, 128);
    }
    {
        long long waves = ((long long)N + 3) / 4;        // c8=16
        int blocks = (int)((waves + 3) / 4);
        gather_relu_f16_kernel<<<blocks, 256, 0, stream>>>(
            (const float4*)hbuf, (float4*)gbuf, row_ptr, esorted, disq, b2, N, 16);
    }

    // --- FC head ---
    final_fc_kernel<<<1024, 256, 0, stream>>>(gbuf, Wfc, bfc, out, N);
}

// Round 5
// 279.842 us; speedup vs baseline: 10.1494x; 1.2987x over previous
//
#include <hip/hip_runtime.h>

// ---------------------------------------------------------------------------
// GCN 2-layer + FC head. CSR gather + f16 MFMA GEMMs; fp32 accumulation.
//   s = rsqrt(1 + indeg)
//   h  = f16((x @ W) * s[row])          (MFMA GEMM, epilogue row-scale)
//   a  = h[i] + sum_{j->i} h[j]         (CSR gather, fp32 acc)
//   h' = f16(relu(s[i]*a + b))
//   out = h2' @ Wfc + bfc               (fp32)
// CSR built per-launch: count -> 3-phase hierarchical exclusive scan -> fill.
// ---------------------------------------------------------------------------

typedef _Float16 f16;
typedef __attribute__((ext_vector_type(8))) _Float16 f16x8;
typedef __attribute__((ext_vector_type(4))) float f32x4;

// ---------------- CSR build ----------------
__global__ void count_kernel(const int* __restrict__ dst, int* __restrict__ cnt,
                             int e) {
    for (int i = blockIdx.x * blockDim.x + threadIdx.x; i < e;
         i += gridDim.x * blockDim.x)
        atomicAdd(&cnt[dst[i]], 1);
}

__global__ void disq_kernel(const int* __restrict__ cnt, float* __restrict__ disq,
                            int n) {
    int i = blockIdx.x * blockDim.x + threadIdx.x;
    if (i < n) disq[i] = rsqrtf(1.0f + (float)cnt[i]);
}

// Phase 1: per-block (256 thr x 4 elem = 1024) local exclusive scan + totals.
__global__ void scan1_kernel(const int* __restrict__ cnt, int* __restrict__ local,
                             int* __restrict__ partials, int n) {
    __shared__ int lds[256];
    int base = blockIdx.x * 1024;
    int t = threadIdx.x;
    int v[4];
    int sum = 0;
    #pragma unroll
    for (int j = 0; j < 4; j++) {
        int i = base + t * 4 + j;
        v[j] = (i < n) ? cnt[i] : 0;
        sum += v[j];
    }
    lds[t] = sum;
    __syncthreads();
    for (int off = 1; off < 256; off <<= 1) {
        int x = (t >= off) ? lds[t - off] : 0;
        __syncthreads();
        lds[t] += x;
        __syncthreads();
    }
    int excl = lds[t] - sum;
    if (t == 255) partials[blockIdx.x] = lds[255];
    int run = excl;
    #pragma unroll
    for (int j = 0; j < 4; j++) {
        int i = base + t * 4 + j;
        if (i < n) local[i] = run;
        run += v[j];
    }
}

// Phase 2: single block scans the block totals (nb <= 1024) -> exclusive.
__global__ void scan2_kernel(int* __restrict__ partials, int nb) {
    __shared__ int lds[1024];
    int t = threadIdx.x;
    int v = (t < nb) ? partials[t] : 0;
    lds[t] = v;
    __syncthreads();
    for (int off = 1; off < 1024; off <<= 1) {
        int x = (t >= off) ? lds[t - off] : 0;
        __syncthreads();
        lds[t] += x;
        __syncthreads();
    }
    if (t < nb) partials[t] = lds[t] - v;
}

// Phase 3: add block offsets -> row_ptr, cursor; row_ptr[n] = E.
__global__ void scan3_kernel(const int* __restrict__ local,
                             const int* __restrict__ partials,
                             int* __restrict__ row_ptr, int* __restrict__ cursor,
                             int n, int e_total) {
    int base = blockIdx.x * 1024;
    int add = partials[blockIdx.x];
    int t = threadIdx.x;
    #pragma unroll
    for (int j = 0; j < 4; j++) {
        int i = base + t * 4 + j;
        if (i < n) {
            int p = local[i] + add;
            row_ptr[i] = p;
            cursor[i] = p;
        }
    }
    if (blockIdx.x == 0 && t == 0) row_ptr[n] = e_total;
}

__global__ void csr_fill_kernel(const int* __restrict__ src, const int* __restrict__ dst,
                                int* __restrict__ cursor, int* __restrict__ esorted,
                                int e) {
    for (int i = blockIdx.x * blockDim.x + threadIdx.x; i < e;
         i += gridDim.x * blockDim.x) {
        int d = dst[i];
        int pos = atomicAdd(&cursor[d], 1);
        esorted[pos] = src[i];
    }
}

// ---------------- dtype conversion ----------------
__global__ void cvt_f32_f16_kernel(const float4* __restrict__ in,
                                   f16* __restrict__ out, long long n4) {
    long long i = blockIdx.x * (long long)blockDim.x + threadIdx.x;
    if (i >= n4) return;
    float4 v = in[i];
    union { f16 h[4]; short4 s; } u;
    u.h[0] = (f16)v.x; u.h[1] = (f16)v.y; u.h[2] = (f16)v.z; u.h[3] = (f16)v.w;
    *(short4*)(out + i * 4) = u.s;
}

// Wt[n][k] = (f16) W[k][n]
__global__ void cvt_wt_kernel(const float* __restrict__ W, f16* __restrict__ Wt,
                              int K, int Nc) {
    int i = blockIdx.x * blockDim.x + threadIdx.x;
    if (i >= K * Nc) return;
    int n = i / K, k = i - n * K;
    Wt[i] = (f16)W[(long long)k * Nc + n];
}

// ---------------- f16 MFMA GEMM ----------------
// C[M][Nc] = f16( (A[M][K] @ Bt[Nc][K]^T) * rowscale[m] )
// Block: 256 thr (4 waves, 2x2), tile 128x64, BK=64, mfma 16x16x32 f16.
__global__ __launch_bounds__(256)
void gemm_f16_kernel(const f16* __restrict__ A,
                     const f16* __restrict__ Bt,
                     f16* __restrict__ C,
                     const float* __restrict__ rowscale,
                     int M, int K, int Nc) {
    __shared__ __align__(16) char smem[(128 * 64 + 64 * 64) * 2]; // As 16KB + Bs 8KB
    char* As = smem;                 // [128 rows][64 f16] = 128B rows, swizzled
    char* Bs = smem + 128 * 64 * 2;  // [64 cols ][64 f16] = 128B rows, swizzled
    const int tid = threadIdx.x;
    const int lane = tid & 63;
    const int wid = tid >> 6;
    const int wr = wid >> 1;   // 0..1  -> 64-row half
    const int wc = wid & 1;    // 0..1  -> 32-col half
    const int row0 = blockIdx.y * 128;
    const int col0 = blockIdx.x * 64;

    f32x4 acc[4][2];
    #pragma unroll
    for (int mr = 0; mr < 4; mr++)
        #pragma unroll
        for (int nr = 0; nr < 2; nr++)
            acc[mr][nr] = (f32x4){0.f, 0.f, 0.f, 0.f};

    for (int k0 = 0; k0 < K; k0 += 64) {
        #pragma unroll
        for (int i = 0; i < 4; i++) {
            int flat = tid + i * 256;
            int r = flat >> 3, g = flat & 7;
            int gr = row0 + r;
            float4 v = {0.f, 0.f, 0.f, 0.f};
            if (gr < M) v = *(const float4*)(A + (long long)gr * K + k0 + g * 8);
            *(float4*)(As + r * 128 + ((g * 16) ^ ((r & 7) << 4))) = v;
        }
        #pragma unroll
        for (int i = 0; i < 2; i++) {
            int flat = tid + i * 256;
            int nn = flat >> 3, g = flat & 7;
            float4 v = *(const float4*)(Bt + (long long)(col0 + nn) * K + k0 + g * 8);
            *(float4*)(Bs + nn * 128 + ((g * 16) ^ ((nn & 7) << 4))) = v;
        }
        __syncthreads();
        #pragma unroll
        for (int ks = 0; ks < 2; ks++) {
            const int kb = (ks * 32 + ((lane >> 4) * 8)) * 2;  // byte-in-row
            f16x8 af[4], bf[2];
            #pragma unroll
            for (int mr = 0; mr < 4; mr++) {
                int r = wr * 64 + mr * 16 + (lane & 15);
                af[mr] = *(const f16x8*)(As + r * 128 + (kb ^ ((r & 7) << 4)));
            }
            #pragma unroll
            for (int nr = 0; nr < 2; nr++) {
                int c = wc * 32 + nr * 16 + (lane & 15);
                bf[nr] = *(const f16x8*)(Bs + c * 128 + (kb ^ ((c & 7) << 4)));
            }
            #pragma unroll
            for (int mr = 0; mr < 4; mr++)
                #pragma unroll
                for (int nr = 0; nr < 2; nr++)
                    acc[mr][nr] = __builtin_amdgcn_mfma_f32_16x16x32_f16(
                        af[mr], bf[nr], acc[mr][nr], 0, 0, 0);
        }
        __syncthreads();
    }
    // epilogue: C/D map col=lane&15, row=(lane>>4)*4+reg  [m89-verified]
    #pragma unroll
    for (int mr = 0; mr < 4; mr++) {
        #pragma unroll
        for (int reg = 0; reg < 4; reg++) {
            int row = row0 + wr * 64 + mr * 16 + (lane >> 4) * 4 + reg;
            if (row < M) {
                float s = rowscale[row];
                int col = col0 + wc * 32 + (lane & 15);
                #pragma unroll
                for (int nr = 0; nr < 2; nr++)
                    C[(long long)row * Nc + col + nr * 16] =
                        (f16)(acc[mr][nr][reg] * s);
            }
        }
    }
}

// ---------------- CSR gather + bias + relu (f16 rows) ----------------
__global__ void gather_relu_f16_kernel(const float4* __restrict__ h,
                                       float4* __restrict__ out,
                                       const int* __restrict__ row_ptr,
                                       const int* __restrict__ esorted,
                                       const float* __restrict__ disq,
                                       const float* __restrict__ bias,
                                       int n, int c8) {
    int lane = threadIdx.x & 63;
    long long wave = (blockIdx.x * (long long)blockDim.x + threadIdx.x) >> 6;
    int epw = 64 / c8;
    int sub = lane / c8;
    int sl = lane - sub * c8;
    long long node = wave * epw + sub;
    if (node >= n) return;
    int beg = row_ptr[node], end = row_ptr[node + 1];
    float acc[8];
    {
        float4 v = h[node * c8 + sl];
        const f16* hp = (const f16*)&v;
        #pragma unroll
        for (int j = 0; j < 8; j++) acc[j] = (float)hp[j];
    }
    for (int e = beg; e < end; e++) {
        int s = esorted[e];
        float4 v = h[(long long)s * c8 + sl];
        const f16* hp = (const f16*)&v;
        #pragma unroll
        for (int j = 0; j < 8; j++) acc[j] += (float)hp[j];
    }
    float sc = disq[node];
    const float4* b4 = (const float4*)(bias + sl * 8);
    float4 b0 = b4[0], b1 = b4[1];
    float bb[8] = {b0.x, b0.y, b0.z, b0.w, b1.x, b1.y, b1.z, b1.w};
    union { float4 f4; f16 hh[8]; } o;
    #pragma unroll
    for (int j = 0; j < 8; j++)
        o.hh[j] = (f16)fmaxf(fmaf(acc[j], sc, bb[j]), 0.0f);
    out[node * c8 + sl] = o.f4;
}

// ---------------- FC head ----------------
__global__ void final_fc_kernel(const f16* __restrict__ h,   // [N][128] f16
                                const float* __restrict__ Wfc,  // [128,6]
                                const float* __restrict__ bfc,
                                float* __restrict__ out, int n) {
    __shared__ float wf[128 * 6];
    for (int i = threadIdx.x; i < 128 * 6; i += blockDim.x) wf[i] = Wfc[i];
    __syncthreads();
    int lane = threadIdx.x & 63;
    int wave = (blockIdx.x * blockDim.x + threadIdx.x) >> 6;
    int nwaves = (gridDim.x * blockDim.x) >> 6;
    for (int node = wave; node < n; node += nwaves) {
        const f16* hp = h + (long long)node * 128 + lane * 2;
        float v0 = (float)hp[0], v1 = (float)hp[1];
        float acc[6];
        #pragma unroll
        for (int j = 0; j < 6; j++)
            acc[j] = v0 * wf[(2 * lane) * 6 + j] + v1 * wf[(2 * lane + 1) * 6 + j];
        #pragma unroll
        for (int off = 32; off >= 1; off >>= 1)
            #pragma unroll
            for (int j = 0; j < 6; j++) acc[j] += __shfl_down(acc[j], off);
        if (lane == 0) {
            #pragma unroll
            for (int j = 0; j < 6; j++)
                out[(long long)node * 6 + j] = acc[j] + bfc[j];
        }
    }
}

extern "C" void kernel_launch(void* const* d_in, const int* in_sizes, int n_in,
                              void* d_out, int out_size, void* d_ws, size_t ws_size,
                              hipStream_t stream) {
    const float* x   = (const float*)d_in[0];
    const float* W1  = (const float*)d_in[1];
    const float* b1  = (const float*)d_in[2];
    const float* W2  = (const float*)d_in[3];
    const float* b2  = (const float*)d_in[4];
    const float* Wfc = (const float*)d_in[5];
    const float* bfc = (const float*)d_in[6];
    const int* edges = (const int*)d_in[7];

    const int N = in_sizes[0] / 128;       // 50000
    const int E = in_sizes[7] / 2;         // 500000
    const int* e_src = edges;
    const int* e_dst = edges + E;

    char* ws = (char*)d_ws;
    size_t off = 0;
    auto alloc = [&](size_t bytes) {
        void* p = ws + off;
        off += (bytes + 255) & ~(size_t)255;
        return p;
    };
    const int NB = (N + 1023) / 1024;                    // scan blocks (49)
    float* disq     = (float*)alloc((size_t)N * 4);
    int*   cnt      = (int*)  alloc((size_t)N * 4);
    int*   slocal   = (int*)  alloc((size_t)N * 4);
    int*   partials = (int*)  alloc((size_t)NB * 4);
    int*   row_ptr  = (int*)  alloc((size_t)(N + 1) * 4);
    int*   cursor   = (int*)  alloc((size_t)N * 4);
    int*   esorted  = (int*)  alloc((size_t)E * 4);
    f16*   x_h      = (f16*)  alloc((size_t)N * 128 * 2);
    f16*   wt1      = (f16*)  alloc((size_t)256 * 128 * 2);  // [256][128]
    f16*   wt2      = (f16*)  alloc((size_t)128 * 256 * 2);  // [128][256]
    f16*   hbuf     = (f16*)  alloc((size_t)N * 256 * 2);    // GEMM out (scaled)
    f16*   gbuf     = (f16*)  alloc((size_t)N * 256 * 2);    // gather out
    (void)ws_size; (void)n_in;

    float* out = (float*)d_out; (void)out_size;

    // --- CSR + degree scales ---
    hipMemsetAsync(cnt, 0, (size_t)N * sizeof(int), stream);
    count_kernel<<<2048, 256, 0, stream>>>(e_dst, cnt, E);
    disq_kernel<<<(N + 255) / 256, 256, 0, stream>>>(cnt, disq, N);
    scan1_kernel<<<NB, 256, 0, stream>>>(cnt, slocal, partials, N);
    scan2_kernel<<<1, 1024, 0, stream>>>(partials, NB);
    scan3_kernel<<<NB, 256, 0, stream>>>(slocal, partials, row_ptr, cursor, N, E);
    csr_fill_kernel<<<2048, 256, 0, stream>>>(e_src, e_dst, cursor, esorted, E);

    // --- conversions ---
    {
        long long n4 = (long long)N * 128 / 4;
        cvt_f32_f16_kernel<<<(int)((n4 + 255) / 256), 256, 0, stream>>>(
            (const float4*)x, x_h, n4);
    }
    cvt_wt_kernel<<<(128 * 256 + 255) / 256, 256, 0, stream>>>(W1, wt1, 128, 256);
    cvt_wt_kernel<<<(256 * 128 + 255) / 256, 256, 0, stream>>>(W2, wt2, 256, 128);

    // --- layer 1: h = (x@W1)*s -> hbuf [N,256] f16 ; gather -> gbuf ---
    {
        dim3 g(256 / 64, (N + 127) / 128);
        gemm_f16_kernel<<<g, 256, 0, stream>>>(x_h, wt1, hbuf, disq, N, 128, 256);
    }
    {
        long long waves = ((long long)N + 1) / 2;        // c8=32
        int blocks = (int)((waves + 3) / 4);
        gather_relu_f16_kernel<<<blocks, 256, 0, stream>>>(
            (const float4*)hbuf, (float4*)gbuf, row_ptr, esorted, disq, b1, N, 32);
    }

    // --- layer 2: h2 = (h1@W2)*s -> hbuf [N,128] f16 ; gather -> gbuf ---
    {
        dim3 g(128 / 64, (N + 127) / 128);
        gemm_f16_kernel<<<g, 256, 0, stream>>>(gbuf, wt2, hbuf, disq, N, 256, 128);
    }
    {
        long long waves = ((long long)N + 3) / 4;        // c8=16
        int blocks = (int)((waves + 3) / 4);
        gather_relu_f16_kernel<<<blocks, 256, 0, stream>>>(
            (const float4*)hbuf, (float4*)gbuf, row_ptr, esorted, disq, b2, N, 16);
    }

    // --- FC head ---
    final_fc_kernel<<<1024, 256, 0, stream>>>(gbuf, Wfc, bfc, out, N);
}

// Round 7
// 240.190 us; speedup vs baseline: 11.8249x; 1.1651x over previous
//
#include <hip/hip_runtime.h>

// ---------------------------------------------------------------------------
// GCN 2-layer + FC head. f16 MFMA GEMMs, CSR gather, fp32 accumulation.
// Layer 1 reordered (aggregate-first):  A_hat(XW) = (A_hat X)W
//   xs   = f16(s.x)                     [N,128]
//   agg1 = xs[i] + sum_{j->i} xs[j]     (gather, 256B rows)
//   h1   = f16(relu(s.(agg1@W1) + b1))  (GEMM epilogue fused)   [N,256]
//   t    = f16(s.(h1@W2))               (GEMM epilogue)         [N,128]
//   agg2 = t[i] + sum t[j]; h2 = relu(s.agg2 + b2)
//   out  = h2 @ Wfc + bfc               (fused into gather2)    [N,6]
// ---------------------------------------------------------------------------

typedef _Float16 f16;
typedef __attribute__((ext_vector_type(8))) _Float16 f16x8;
typedef __attribute__((ext_vector_type(4))) float f32x4;

// ---------------- CSR build ----------------
__global__ void count_kernel(const int* __restrict__ dst, int* __restrict__ cnt,
                             int e) {
    for (int i = blockIdx.x * blockDim.x + threadIdx.x; i < e;
         i += gridDim.x * blockDim.x)
        atomicAdd(&cnt[dst[i]], 1);
}

// Phase 1: per-block (256 thr x 4) local exclusive scan + totals + disq.
__global__ void scan1_kernel(const int* __restrict__ cnt, int* __restrict__ local,
                             int* __restrict__ partials, float* __restrict__ disq,
                             int n) {
    __shared__ int lds[256];
    int base = blockIdx.x * 1024;
    int t = threadIdx.x;
    int v[4];
    int sum = 0;
    #pragma unroll
    for (int j = 0; j < 4; j++) {
        int i = base + t * 4 + j;
        v[j] = (i < n) ? cnt[i] : 0;
        if (i < n) disq[i] = rsqrtf(1.0f + (float)v[j]);
        sum += v[j];
    }
    lds[t] = sum;
    __syncthreads();
    for (int off = 1; off < 256; off <<= 1) {
        int x = (t >= off) ? lds[t - off] : 0;
        __syncthreads();
        lds[t] += x;
        __syncthreads();
    }
    int excl = lds[t] - sum;
    if (t == 255) partials[blockIdx.x] = lds[255];
    int run = excl;
    #pragma unroll
    for (int j = 0; j < 4; j++) {
        int i = base + t * 4 + j;
        if (i < n) local[i] = run;
        run += v[j];
    }
}

// Phase 2: single block scans block totals (nb <= 1024) -> exclusive.
__global__ void scan2_kernel(int* __restrict__ partials, int nb) {
    __shared__ int lds[1024];
    int t = threadIdx.x;
    int v = (t < nb) ? partials[t] : 0;
    lds[t] = v;
    __syncthreads();
    for (int off = 1; off < 1024; off <<= 1) {
        int x = (t >= off) ? lds[t - off] : 0;
        __syncthreads();
        lds[t] += x;
        __syncthreads();
    }
    if (t < nb) partials[t] = lds[t] - v;
}

// Phase 3: add block offsets -> row_ptr, cursor; row_ptr[n] = E.
__global__ void scan3_kernel(const int* __restrict__ local,
                             const int* __restrict__ partials,
                             int* __restrict__ row_ptr, int* __restrict__ cursor,
                             int n, int e_total) {
    int base = blockIdx.x * 1024;
    int add = partials[blockIdx.x];
    int t = threadIdx.x;
    #pragma unroll
    for (int j = 0; j < 4; j++) {
        int i = base + t * 4 + j;
        if (i < n) {
            int p = local[i] + add;
            row_ptr[i] = p;
            cursor[i] = p;
        }
    }
    if (blockIdx.x == 0 && t == 0) row_ptr[n] = e_total;
}

__global__ void csr_fill_kernel(const int* __restrict__ src, const int* __restrict__ dst,
                                int* __restrict__ cursor, int* __restrict__ esorted,
                                int e) {
    for (int i = blockIdx.x * blockDim.x + threadIdx.x; i < e;
         i += gridDim.x * blockDim.x) {
        int d = dst[i];
        int pos = atomicAdd(&cursor[d], 1);
        esorted[pos] = src[i];
    }
}

// ---------------- conversions ----------------
// xs = f16(x * disq[row]), 4 floats/thread, row = i/32 (128 cols).
__global__ void scale_cvt_kernel(const float4* __restrict__ in,
                                 const float* __restrict__ disq,
                                 f16* __restrict__ out, long long n4) {
    long long i = blockIdx.x * (long long)blockDim.x + threadIdx.x;
    if (i >= n4) return;
    float4 v = in[i];
    float s = disq[i >> 5];
    union { f16 h[4]; short4 s4; } u;
    u.h[0] = (f16)(v.x * s); u.h[1] = (f16)(v.y * s);
    u.h[2] = (f16)(v.z * s); u.h[3] = (f16)(v.w * s);
    *(short4*)(out + i * 4) = u.s4;
}

// Wt[n][k] = (f16) W[k][n]
__global__ void cvt_wt_kernel(const float* __restrict__ W, f16* __restrict__ Wt,
                              int K, int Nc) {
    int i = blockIdx.x * blockDim.x + threadIdx.x;
    if (i >= K * Nc) return;
    int n = i / K, k = i - n * K;
    Wt[i] = (f16)W[(long long)k * Nc + n];
}

// ---------------- f16 MFMA GEMM ----------------
// C[M][Nc] = f16( epilogue( (A[M][K] @ Bt[Nc][K]^T) ) )
// MODE 0: *rowscale            MODE 1: relu(*rowscale + bias[col])
// Block: 256 thr (4 waves 2x2), tile 128x64, BK=64, mfma 16x16x32 f16.
template <int MODE>
__global__ __launch_bounds__(256)
void gemm_f16_kernel(const f16* __restrict__ A,
                     const f16* __restrict__ Bt,
                     f16* __restrict__ C,
                     const float* __restrict__ rowscale,
                     const float* __restrict__ bias,
                     int M, int K, int Nc) {
    __shared__ __align__(16) char smem[(128 * 64 + 64 * 64) * 2]; // As 16KB + Bs 8KB
    char* As = smem;                 // [128 rows][64 f16], 128B rows, XOR-swizzled
    char* Bs = smem + 128 * 64 * 2;  // [64 cols ][64 f16]
    const int tid = threadIdx.x;
    const int lane = tid & 63;
    const int wid = tid >> 6;
    const int wr = wid >> 1;
    const int wc = wid & 1;
    const int row0 = blockIdx.y * 128;
    const int col0 = blockIdx.x * 64;

    f32x4 acc[4][2];
    #pragma unroll
    for (int mr = 0; mr < 4; mr++)
        #pragma unroll
        for (int nr = 0; nr < 2; nr++)
            acc[mr][nr] = (f32x4){0.f, 0.f, 0.f, 0.f};

    for (int k0 = 0; k0 < K; k0 += 64) {
        #pragma unroll
        for (int i = 0; i < 4; i++) {
            int flat = tid + i * 256;
            int r = flat >> 3, g = flat & 7;
            int gr = row0 + r;
            float4 v = {0.f, 0.f, 0.f, 0.f};
            if (gr < M) v = *(const float4*)(A + (long long)gr * K + k0 + g * 8);
            *(float4*)(As + r * 128 + ((g * 16) ^ ((r & 7) << 4))) = v;
        }
        #pragma unroll
        for (int i = 0; i < 2; i++) {
            int flat = tid + i * 256;
            int nn = flat >> 3, g = flat & 7;
            float4 v = *(const float4*)(Bt + (long long)(col0 + nn) * K + k0 + g * 8);
            *(float4*)(Bs + nn * 128 + ((g * 16) ^ ((nn & 7) << 4))) = v;
        }
        __syncthreads();
        #pragma unroll
        for (int ks = 0; ks < 2; ks++) {
            const int kb = (ks * 32 + ((lane >> 4) * 8)) * 2;
            f16x8 af[4], bf[2];
            #pragma unroll
            for (int mr = 0; mr < 4; mr++) {
                int r = wr * 64 + mr * 16 + (lane & 15);
                af[mr] = *(const f16x8*)(As + r * 128 + (kb ^ ((r & 7) << 4)));
            }
            #pragma unroll
            for (int nr = 0; nr < 2; nr++) {
                int c = wc * 32 + nr * 16 + (lane & 15);
                bf[nr] = *(const f16x8*)(Bs + c * 128 + (kb ^ ((c & 7) << 4)));
            }
            #pragma unroll
            for (int mr = 0; mr < 4; mr++)
                #pragma unroll
                for (int nr = 0; nr < 2; nr++)
                    acc[mr][nr] = __builtin_amdgcn_mfma_f32_16x16x32_f16(
                        af[mr], bf[nr], acc[mr][nr], 0, 0, 0);
        }
        __syncthreads();
    }
    // epilogue: C/D map col=lane&15, row=(lane>>4)*4+reg  [m89-verified]
    float bv[2] = {0.f, 0.f};
    if (MODE == 1) {
        #pragma unroll
        for (int nr = 0; nr < 2; nr++)
            bv[nr] = bias[col0 + wc * 32 + nr * 16 + (lane & 15)];
    }
    #pragma unroll
    for (int mr = 0; mr < 4; mr++) {
        #pragma unroll
        for (int reg = 0; reg < 4; reg++) {
            int row = row0 + wr * 64 + mr * 16 + (lane >> 4) * 4 + reg;
            if (row < M) {
                float s = rowscale[row];
                int col = col0 + wc * 32 + (lane & 15);
                #pragma unroll
                for (int nr = 0; nr < 2; nr++) {
                    float v = acc[mr][nr][reg] * s;
                    if (MODE == 1) v = fmaxf(v + bv[nr], 0.0f);
                    C[(long long)row * Nc + col + nr * 16] = (f16)v;
                }
            }
        }
    }
}

// ---------------- gather (pure sum, f16 rows of c8 float4s) ----------------
__global__ void gather_sum_f16_kernel(const float4* __restrict__ h,
                                      float4* __restrict__ out,
                                      const int* __restrict__ row_ptr,
                                      const int* __restrict__ esorted,
                                      int n, int c8) {
    int lane = threadIdx.x & 63;
    long long wave = (blockIdx.x * (long long)blockDim.x + threadIdx.x) >> 6;
    int epw = 64 / c8;
    int sub = lane / c8;
    int sl = lane - sub * c8;
    long long node = wave * epw + sub;
    if (node >= n) return;
    int beg = row_ptr[node], end = row_ptr[node + 1];
    float acc[8];
    {
        float4 v = h[node * c8 + sl];
        const f16* hp = (const f16*)&v;
        #pragma unroll
        for (int j = 0; j < 8; j++) acc[j] = (float)hp[j];
    }
    for (int e = beg; e < end; e++) {
        int s = esorted[e];
        float4 v = h[(long long)s * c8 + sl];
        const f16* hp = (const f16*)&v;
        #pragma unroll
        for (int j = 0; j < 8; j++) acc[j] += (float)hp[j];
    }
    union { float4 f4; f16 hh[8]; } o;
    #pragma unroll
    for (int j = 0; j < 8; j++) o.hh[j] = (f16)acc[j];
    out[node * c8 + sl] = o.f4;
}

// ---------------- gather2 + relu + FC head (c8 = 16 fixed) ----------------
// h2 = relu(disq[node]*(t[node]+sum t[src]) + b2);  out = h2 @ Wfc + bfc
__global__ void gather_fc_kernel(const float4* __restrict__ t,
                                 const int* __restrict__ row_ptr,
                                 const int* __restrict__ esorted,
                                 const float* __restrict__ disq,
                                 const float* __restrict__ b2,
                                 const float* __restrict__ Wfc,   // [128][6]
                                 const float* __restrict__ bfc,   // [6]
                                 float* __restrict__ out, int n) {
    __shared__ float wf[6 * 132];    // transposed [6][128], padded row 132
    for (int i = threadIdx.x; i < 6 * 128; i += 256) {
        int k = i >> 7, ch = i & 127;
        wf[k * 132 + ch] = Wfc[ch * 6 + k];
    }
    __syncthreads();
    int lane = threadIdx.x & 63;
    long long wave = (blockIdx.x * (long long)blockDim.x + threadIdx.x) >> 6;
    int sub = lane >> 4;
    int sl = lane & 15;
    long long node = wave * 4 + sub;
    if (node >= n) return;
    int beg = row_ptr[node], end = row_ptr[node + 1];
    float acc[8];
    {
        float4 v = t[node * 16 + sl];
        const f16* hp = (const f16*)&v;
        #pragma unroll
        for (int j = 0; j < 8; j++) acc[j] = (float)hp[j];
    }
    for (int e = beg; e < end; e++) {
        int s = esorted[e];
        float4 v = t[(long long)s * 16 + sl];
        const f16* hp = (const f16*)&v;
        #pragma unroll
        for (int j = 0; j < 8; j++) acc[j] += (float)hp[j];
    }
    float sc = disq[node];
    const float4* b4 = (const float4*)(b2 + sl * 8);
    float4 bb0 = b4[0], bb1 = b4[1];
    float bb[8] = {bb0.x, bb0.y, bb0.z, bb0.w, bb1.x, bb1.y, bb1.z, bb1.w};
    float h2[8];
    #pragma unroll
    for (int j = 0; j < 8; j++)
        h2[j] = fmaxf(fmaf(acc[j], sc, bb[j]), 0.0f);
    float p[6];
    #pragma unroll
    for (int k = 0; k < 6; k++) {
        float s = 0.f;
        #pragma unroll
        for (int j = 0; j < 8; j++) s += h2[j] * wf[k * 132 + sl * 8 + j];
        p[k] = s;
    }
    #pragma unroll
    for (int off = 8; off >= 1; off >>= 1)
        #pragma unroll
        for (int k = 0; k < 6; k++) p[k] += __shfl_down(p[k], off);
    if (sl == 0) {
        #pragma unroll
        for (int k = 0; k < 6; k++)
            out[(long long)node * 6 + k] = p[k] + bfc[k];
    }
}

extern "C" void kernel_launch(void* const* d_in, const int* in_sizes, int n_in,
                              void* d_out, int out_size, void* d_ws, size_t ws_size,
                              hipStream_t stream) {
    const float* x   = (const float*)d_in[0];
    const float* W1  = (const float*)d_in[1];
    const float* b1  = (const float*)d_in[2];
    const float* W2  = (const float*)d_in[3];
    const float* b2  = (const float*)d_in[4];
    const float* Wfc = (const float*)d_in[5];
    const float* bfc = (const float*)d_in[6];
    const int* edges = (const int*)d_in[7];

    const int N = in_sizes[0] / 128;       // 50000
    const int E = in_sizes[7] / 2;         // 500000
    const int* e_src = edges;
    const int* e_dst = edges + E;

    char* ws = (char*)d_ws;
    size_t off = 0;
    auto alloc = [&](size_t bytes) {
        void* p = ws + off;
        off += (bytes + 255) & ~(size_t)255;
        return p;
    };
    const int NB = (N + 1023) / 1024;
    float* disq     = (float*)alloc((size_t)N * 4);
    int*   cnt      = (int*)  alloc((size_t)N * 4);
    int*   slocal   = (int*)  alloc((size_t)N * 4);
    int*   partials = (int*)  alloc((size_t)NB * 4);
    int*   row_ptr  = (int*)  alloc((size_t)(N + 1) * 4);
    int*   cursor   = (int*)  alloc((size_t)N * 4);
    int*   esorted  = (int*)  alloc((size_t)E * 4);
    f16*   xs       = (f16*)  alloc((size_t)N * 128 * 2);
    f16*   wt1      = (f16*)  alloc((size_t)256 * 128 * 2);  // [256][128]
    f16*   wt2      = (f16*)  alloc((size_t)128 * 256 * 2);  // [128][256]
    f16*   agg1     = (f16*)  alloc((size_t)N * 128 * 2);
    f16*   h1       = (f16*)  alloc((size_t)N * 256 * 2);
    f16*   tbuf     = (f16*)  alloc((size_t)N * 128 * 2);
    (void)ws_size; (void)n_in;

    float* out = (float*)d_out; (void)out_size;

    // --- CSR + degree scales ---
    hipMemsetAsync(cnt, 0, (size_t)N * sizeof(int), stream);
    count_kernel<<<2048, 256, 0, stream>>>(e_dst, cnt, E);
    scan1_kernel<<<NB, 256, 0, stream>>>(cnt, slocal, partials, disq, N);
    scan2_kernel<<<1, 1024, 0, stream>>>(partials, NB);
    scan3_kernel<<<NB, 256, 0, stream>>>(slocal, partials, row_ptr, cursor, N, E);
    csr_fill_kernel<<<2048, 256, 0, stream>>>(e_src, e_dst, cursor, esorted, E);

    // --- conversions ---
    {
        long long n4 = (long long)N * 128 / 4;
        scale_cvt_kernel<<<(int)((n4 + 255) / 256), 256, 0, stream>>>(
            (const float4*)x, disq, xs, n4);
    }
    cvt_wt_kernel<<<(128 * 256 + 255) / 256, 256, 0, stream>>>(W1, wt1, 128, 256);
    cvt_wt_kernel<<<(256 * 128 + 255) / 256, 256, 0, stream>>>(W2, wt2, 256, 128);

    // --- layer 1: gather xs -> agg1 ; GEMM (+scale+bias+relu) -> h1 ---
    {
        long long waves = ((long long)N + 3) / 4;        // c8=16
        int blocks = (int)((waves + 3) / 4);
        gather_sum_f16_kernel<<<blocks, 256, 0, stream>>>(
            (const float4*)xs, (float4*)agg1, row_ptr, esorted, N, 16);
    }
    {
        dim3 g(256 / 64, (N + 127) / 128);
        gemm_f16_kernel<1><<<g, 256, 0, stream>>>(agg1, wt1, h1, disq, b1,
                                                  N, 128, 256);
    }

    // --- layer 2: GEMM (+scale) -> tbuf ; gather + relu + FC -> out ---
    {
        dim3 g(128 / 64, (N + 127) / 128);
        gemm_f16_kernel<0><<<g, 256, 0, stream>>>(h1, wt2, tbuf, disq, nullptr,
                                                  N, 256, 128);
    }
    {
        long long waves = ((long long)N + 3) / 4;        // c8=16
        int blocks = (int)((waves + 3) / 4);
        gather_fc_kernel<<<blocks, 256, 0, stream>>>(
            (const float4*)tbuf, row_ptr, esorted, disq, b2, Wfc, bfc, out, N);
    }
}

// Round 8
// 234.846 us; speedup vs baseline: 12.0939x; 1.0228x over previous
//
#include <hip/hip_runtime.h>

// ---------------------------------------------------------------------------
// GCN 2-layer + FC head. f16 MFMA GEMMs, CSR gather, fp32 accumulation.
// Layer 1 aggregate-first:  A_hat(XW) = (A_hat X)W
//   xs   = f16(s.x)                     [N,128]
//   agg1 = xs[i] + sum_{j->i} xs[j]     (gather, 256B rows, x4 unrolled)
//   h1   = f16(relu(s.(agg1@W1) + b1))  (GEMM epilogue fused)   [N,256]
//   t    = f16(s.(h1@W2))               (GEMM epilogue)         [N,128]
//   out  = relu(s.(t[i]+sum t[j]) + b2) @ Wfc + bfc  (fused)    [N,6]
// GEMM: global_load_lds staging (source-swizzled), double-buffered prefetch.
// ---------------------------------------------------------------------------

typedef _Float16 f16;
typedef __attribute__((ext_vector_type(8))) _Float16 f16x8;
typedef __attribute__((ext_vector_type(4))) float f32x4;

#define GLOAD16(g, l)                                                      \
    __builtin_amdgcn_global_load_lds(                                      \
        (const __attribute__((address_space(1))) void*)(g),                \
        (__attribute__((address_space(3))) void*)(l), 16, 0, 0)

// ---------------- CSR build ----------------
__global__ void count_kernel(const int* __restrict__ dst, int* __restrict__ cnt,
                             int e) {
    for (int i = blockIdx.x * blockDim.x + threadIdx.x; i < e;
         i += gridDim.x * blockDim.x)
        atomicAdd(&cnt[dst[i]], 1);
}

// Phase 1: per-block (256 thr x 4) local exclusive scan + totals + disq.
__global__ void scan1_kernel(const int* __restrict__ cnt, int* __restrict__ local,
                             int* __restrict__ partials, float* __restrict__ disq,
                             int n) {
    __shared__ int lds[256];
    int base = blockIdx.x * 1024;
    int t = threadIdx.x;
    int v[4];
    int sum = 0;
    #pragma unroll
    for (int j = 0; j < 4; j++) {
        int i = base + t * 4 + j;
        v[j] = (i < n) ? cnt[i] : 0;
        if (i < n) disq[i] = rsqrtf(1.0f + (float)v[j]);
        sum += v[j];
    }
    lds[t] = sum;
    __syncthreads();
    for (int off = 1; off < 256; off <<= 1) {
        int x = (t >= off) ? lds[t - off] : 0;
        __syncthreads();
        lds[t] += x;
        __syncthreads();
    }
    int excl = lds[t] - sum;
    if (t == 255) partials[blockIdx.x] = lds[255];
    int run = excl;
    #pragma unroll
    for (int j = 0; j < 4; j++) {
        int i = base + t * 4 + j;
        if (i < n) local[i] = run;
        run += v[j];
    }
}

// Phase 2: single block scans block totals (nb <= 1024) -> exclusive.
__global__ void scan2_kernel(int* __restrict__ partials, int nb) {
    __shared__ int lds[1024];
    int t = threadIdx.x;
    int v = (t < nb) ? partials[t] : 0;
    lds[t] = v;
    __syncthreads();
    for (int off = 1; off < 1024; off <<= 1) {
        int x = (t >= off) ? lds[t - off] : 0;
        __syncthreads();
        lds[t] += x;
        __syncthreads();
    }
    if (t < nb) partials[t] = lds[t] - v;
}

// Phase 3: add block offsets -> row_ptr, cursor; row_ptr[n] = E.
__global__ void scan3_kernel(const int* __restrict__ local,
                             const int* __restrict__ partials,
                             int* __restrict__ row_ptr, int* __restrict__ cursor,
                             int n, int e_total) {
    int base = blockIdx.x * 1024;
    int add = partials[blockIdx.x];
    int t = threadIdx.x;
    #pragma unroll
    for (int j = 0; j < 4; j++) {
        int i = base + t * 4 + j;
        if (i < n) {
            int p = local[i] + add;
            row_ptr[i] = p;
            cursor[i] = p;
        }
    }
    if (blockIdx.x == 0 && t == 0) row_ptr[n] = e_total;
}

__global__ void csr_fill_kernel(const int* __restrict__ src, const int* __restrict__ dst,
                                int* __restrict__ cursor, int* __restrict__ esorted,
                                int e) {
    for (int i = blockIdx.x * blockDim.x + threadIdx.x; i < e;
         i += gridDim.x * blockDim.x) {
        int d = dst[i];
        int pos = atomicAdd(&cursor[d], 1);
        esorted[pos] = src[i];
    }
}

// ---------------- merged conversions ----------------
// [0, n4):            xs = f16(x * disq[row])   (float4 granules, 128 cols)
// [n4, n4+32768):     wt1[n][k] = f16(W1[k][n])   (K=128, Nc=256 -> [256][128])
// [.., +32768):       wt2[n][k] = f16(W2[k][n])   (K=256, Nc=128 -> [128][256])
__global__ void cvt_all_kernel(const float4* __restrict__ x,
                               const float* __restrict__ disq,
                               f16* __restrict__ xs,
                               const float* __restrict__ W1, f16* __restrict__ wt1,
                               const float* __restrict__ W2, f16* __restrict__ wt2,
                               long long n4) {
    long long i = blockIdx.x * (long long)blockDim.x + threadIdx.x;
    if (i < n4) {
        float4 v = x[i];
        float s = disq[i >> 5];
        union { f16 h[4]; short4 s4; } u;
        u.h[0] = (f16)(v.x * s); u.h[1] = (f16)(v.y * s);
        u.h[2] = (f16)(v.z * s); u.h[3] = (f16)(v.w * s);
        *(short4*)(xs + i * 4) = u.s4;
        return;
    }
    long long j = i - n4;
    if (j < 32768) {                 // wt1: n = j>>7 (256), k = j&127
        int nn = (int)(j >> 7), k = (int)(j & 127);
        wt1[j] = (f16)W1[(long long)k * 256 + nn];
        return;
    }
    j -= 32768;
    if (j < 32768) {                 // wt2: n = j>>8 (128), k = j&255
        int nn = (int)(j >> 8), k = (int)(j & 255);
        wt2[j] = (f16)W2[(long long)k * 128 + nn];
    }
}

// ---------------- f16 MFMA GEMM (v2: gload_lds + double buffer) ----------
// C[M][Nc] = f16( epilogue( A[M][K] @ Bt[Nc][K]^T ) )
// MODE 0: *rowscale            MODE 1: relu(*rowscale + bias[col])
// Block: 256 thr (4 waves 2x2), tile 128x64, BK=64, mfma 16x16x32 f16.
// LDS layout (per buffer): As[128 rows][64 f16] then Bs[64][64 f16]; within a
// row, 16B chunk g lives at byte (g*16)^((r&7)<<4) (XOR swizzle). Staging
// keeps LDS dest LINEAR and swizzles the per-lane GLOBAL source (G21).
template <int MODE>
__global__ __launch_bounds__(256)
void gemm_f16_kernel(const f16* __restrict__ A,
                     const f16* __restrict__ Bt,
                     f16* __restrict__ C,
                     const float* __restrict__ rowscale,
                     const float* __restrict__ bias,
                     int M, int K, int Nc) {
    __shared__ __align__(16) char smem[2 * 24 * 1024];   // 2 x (16KB A + 8KB B)
    const int tid = threadIdx.x;
    const int lane = tid & 63;
    const int wid = tid >> 6;
    const int wr = wid >> 1;
    const int wc = wid & 1;
    const int row0 = blockIdx.y * 128;
    const int col0 = blockIdx.x * 64;
    const bool rows_full = (row0 + 128 <= M);

    f32x4 acc[4][2];
    #pragma unroll
    for (int mr = 0; mr < 4; mr++)
        #pragma unroll
        for (int nr = 0; nr < 2; nr++)
            acc[mr][nr] = (f32x4){0.f, 0.f, 0.f, 0.f};

    auto stage = [&](int buf, int k0) {
        char* as = smem + buf * (24 * 1024);
        char* bs = as + 16 * 1024;
        if (rows_full) {
            #pragma unroll
            for (int i = 0; i < 4; i++) {
                int flat = i * 256 + tid;            // 0..1023 (A chunks)
                int r = flat >> 3, gp = flat & 7;
                int g = gp ^ (r & 7);                // inverse-swizzled source
                const f16* src = A + (long long)(row0 + r) * K + k0 + g * 8;
                GLOAD16(src, as + (i * 256 + wid * 64) * 16);
            }
        } else {
            #pragma unroll
            for (int i = 0; i < 4; i++) {
                int flat = i * 256 + tid;
                int r = flat >> 3, gp = flat & 7;
                int g = gp ^ (r & 7);
                int gr = row0 + r;
                float4 v = {0.f, 0.f, 0.f, 0.f};
                if (gr < M) v = *(const float4*)(A + (long long)gr * K + k0 + g * 8);
                *(float4*)(as + flat * 16) = v;      // same linear dest layout
            }
        }
        #pragma unroll
        for (int i = 0; i < 2; i++) {
            int flat = i * 256 + tid;                // 0..511 (B chunks)
            int nn = flat >> 3, gp = flat & 7;
            int g = gp ^ (nn & 7);
            const f16* src = Bt + (long long)(col0 + nn) * K + k0 + g * 8;
            GLOAD16(src, bs + (i * 256 + wid * 64) * 16);
        }
    };

    auto compute = [&](int buf) {
        char* as = smem + buf * (24 * 1024);
        char* bs = as + 16 * 1024;
        #pragma unroll
        for (int ks = 0; ks < 2; ks++) {
            const int kb = (ks * 32 + ((lane >> 4) * 8)) * 2;
            f16x8 af[4], bf[2];
            #pragma unroll
            for (int mr = 0; mr < 4; mr++) {
                int r = wr * 64 + mr * 16 + (lane & 15);
                af[mr] = *(const f16x8*)(as + r * 128 + (kb ^ ((r & 7) << 4)));
            }
            #pragma unroll
            for (int nr = 0; nr < 2; nr++) {
                int c = wc * 32 + nr * 16 + (lane & 15);
                bf[nr] = *(const f16x8*)(bs + c * 128 + (kb ^ ((c & 7) << 4)));
            }
            #pragma unroll
            for (int mr = 0; mr < 4; mr++)
                #pragma unroll
                for (int nr = 0; nr < 2; nr++)
                    acc[mr][nr] = __builtin_amdgcn_mfma_f32_16x16x32_f16(
                        af[mr], bf[nr], acc[mr][nr], 0, 0, 0);
        }
    };

    const int nt = K >> 6;
    stage(0, 0);
    __syncthreads();                                  // drains vmcnt + barrier
    int cur = 0;
    for (int t = 0; t < nt; t++) {
        if (t + 1 < nt) stage(cur ^ 1, (t + 1) * 64); // issue-early prefetch
        compute(cur);
        __syncthreads();
        cur ^= 1;
    }

    // epilogue: C/D map col=lane&15, row=(lane>>4)*4+reg  [m89-verified]
    float bv[2] = {0.f, 0.f};
    if (MODE == 1) {
        #pragma unroll
        for (int nr = 0; nr < 2; nr++)
            bv[nr] = bias[col0 + wc * 32 + nr * 16 + (lane & 15)];
    }
    #pragma unroll
    for (int mr = 0; mr < 4; mr++) {
        #pragma unroll
        for (int reg = 0; reg < 4; reg++) {
            int row = row0 + wr * 64 + mr * 16 + (lane >> 4) * 4 + reg;
            if (row < M) {
                float s = rowscale[row];
                int col = col0 + wc * 32 + (lane & 15);
                #pragma unroll
                for (int nr = 0; nr < 2; nr++) {
                    float v = acc[mr][nr][reg] * s;
                    if (MODE == 1) v = fmaxf(v + bv[nr], 0.0f);
                    C[(long long)row * Nc + col + nr * 16] = (f16)v;
                }
            }
        }
    }
}

// ---------------- gather (pure sum, 128-ch f16 rows, x4 unrolled) --------
__global__ void gather_sum_f16_kernel(const float4* __restrict__ h,
                                      float4* __restrict__ out,
                                      const int* __restrict__ row_ptr,
                                      const int* __restrict__ esorted, int n) {
    int lane = threadIdx.x & 63;
    long long wave = (blockIdx.x * (long long)blockDim.x + threadIdx.x) >> 6;
    int sub = lane >> 4;            // 4 nodes/wave
    int sl = lane & 15;
    long long node = wave * 4 + sub;
    if (node >= n) return;
    int beg = row_ptr[node], end = row_ptr[node + 1];
    float acc[8];
    {
        float4 v = h[node * 16 + sl];
        const f16* hp = (const f16*)&v;
        #pragma unroll
        for (int j = 0; j < 8; j++) acc[j] = (float)hp[j];
    }
    int e = beg;
    for (; e + 4 <= end; e += 4) {  // 4 independent row loads in flight
        int s0 = esorted[e], s1 = esorted[e + 1];
        int s2 = esorted[e + 2], s3 = esorted[e + 3];
        float4 v0 = h[(long long)s0 * 16 + sl];
        float4 v1 = h[(long long)s1 * 16 + sl];
        float4 v2 = h[(long long)s2 * 16 + sl];
        float4 v3 = h[(long long)s3 * 16 + sl];
        const f16 *p0 = (const f16*)&v0, *p1 = (const f16*)&v1;
        const f16 *p2 = (const f16*)&v2, *p3 = (const f16*)&v3;
        #pragma unroll
        for (int j = 0; j < 8; j++)
            acc[j] += (float)p0[j] + (float)p1[j] + (float)p2[j] + (float)p3[j];
    }
    for (; e < end; e++) {
        int s = esorted[e];
        float4 v = h[(long long)s * 16 + sl];
        const f16* hp = (const f16*)&v;
        #pragma unroll
        for (int j = 0; j < 8; j++) acc[j] += (float)hp[j];
    }
    union { float4 f4; f16 hh[8]; } o;
    #pragma unroll
    for (int j = 0; j < 8; j++) o.hh[j] = (f16)acc[j];
    out[node * 16 + sl] = o.f4;
}

// ---------------- gather2 + relu + FC head (x4 unrolled) -----------------
// h2 = relu(disq[node]*(t[node]+sum t[src]) + b2);  out = h2 @ Wfc + bfc
__global__ void gather_fc_kernel(const float4* __restrict__ t,
                                 const int* __restrict__ row_ptr,
                                 const int* __restrict__ esorted,
                                 const float* __restrict__ disq,
                                 const float* __restrict__ b2,
                                 const float* __restrict__ Wfc,   // [128][6]
                                 const float* __restrict__ bfc,   // [6]
                                 float* __restrict__ out, int n) {
    __shared__ float wf[6 * 132];    // transposed [6][128], padded row 132
    for (int i = threadIdx.x; i < 6 * 128; i += 256) {
        int k = i >> 7, ch = i & 127;
        wf[k * 132 + ch] = Wfc[ch * 6 + k];
    }
    __syncthreads();
    int lane = threadIdx.x & 63;
    long long wave = (blockIdx.x * (long long)blockDim.x + threadIdx.x) >> 6;
    int sub = lane >> 4;
    int sl = lane & 15;
    long long node = wave * 4 + sub;
    if (node >= n) return;
    int beg = row_ptr[node], end = row_ptr[node + 1];
    float acc[8];
    {
        float4 v = t[node * 16 + sl];
        const f16* hp = (const f16*)&v;
        #pragma unroll
        for (int j = 0; j < 8; j++) acc[j] = (float)hp[j];
    }
    int e = beg;
    for (; e + 4 <= end; e += 4) {
        int s0 = esorted[e], s1 = esorted[e + 1];
        int s2 = esorted[e + 2], s3 = esorted[e + 3];
        float4 v0 = t[(long long)s0 * 16 + sl];
        float4 v1 = t[(long long)s1 * 16 + sl];
        float4 v2 = t[(long long)s2 * 16 + sl];
        float4 v3 = t[(long long)s3 * 16 + sl];
        const f16 *p0 = (const f16*)&v0, *p1 = (const f16*)&v1;
        const f16 *p2 = (const f16*)&v2, *p3 = (const f16*)&v3;
        #pragma unroll
        for (int j = 0; j < 8; j++)
            acc[j] += (float)p0[j] + (float)p1[j] + (float)p2[j] + (float)p3[j];
    }
    for (; e < end; e++) {
        int s = esorted[e];
        float4 v = t[(long long)s * 16 + sl];
        const f16* hp = (const f16*)&v;
        #pragma unroll
        for (int j = 0; j < 8; j++) acc[j] += (float)hp[j];
    }
    float sc = disq[node];
    const float4* b4 = (const float4*)(b2 + sl * 8);
    float4 bb0 = b4[0], bb1 = b4[1];
    float bb[8] = {bb0.x, bb0.y, bb0.z, bb0.w, bb1.x, bb1.y, bb1.z, bb1.w};
    float h2[8];
    #pragma unroll
    for (int j = 0; j < 8; j++)
        h2[j] = fmaxf(fmaf(acc[j], sc, bb[j]), 0.0f);
    float p[6];
    #pragma unroll
    for (int k = 0; k < 6; k++) {
        float s = 0.f;
        #pragma unroll
        for (int j = 0; j < 8; j++) s += h2[j] * wf[k * 132 + sl * 8 + j];
        p[k] = s;
    }
    #pragma unroll
    for (int off = 8; off >= 1; off >>= 1)
        #pragma unroll
        for (int k = 0; k < 6; k++) p[k] += __shfl_down(p[k], off);
    if (sl == 0) {
        #pragma unroll
        for (int k = 0; k < 6; k++)
            out[(long long)node * 6 + k] = p[k] + bfc[k];
    }
}

extern "C" void kernel_launch(void* const* d_in, const int* in_sizes, int n_in,
                              void* d_out, int out_size, void* d_ws, size_t ws_size,
                              hipStream_t stream) {
    const float* x   = (const float*)d_in[0];
    const float* W1  = (const float*)d_in[1];
    const float* b1  = (const float*)d_in[2];
    const float* W2  = (const float*)d_in[3];
    const float* b2  = (const float*)d_in[4];
    const float* Wfc = (const float*)d_in[5];
    const float* bfc = (const float*)d_in[6];
    const int* edges = (const int*)d_in[7];

    const int N = in_sizes[0] / 128;       // 50000
    const int E = in_sizes[7] / 2;         // 500000
    const int* e_src = edges;
    const int* e_dst = edges + E;

    char* ws = (char*)d_ws;
    size_t off = 0;
    auto alloc = [&](size_t bytes) {
        void* p = ws + off;
        off += (bytes + 255) & ~(size_t)255;
        return p;
    };
    const int NB = (N + 1023) / 1024;
    float* disq     = (float*)alloc((size_t)N * 4);
    int*   cnt      = (int*)  alloc((size_t)N * 4);
    int*   slocal   = (int*)  alloc((size_t)N * 4);
    int*   partials = (int*)  alloc((size_t)NB * 4);
    int*   row_ptr  = (int*)  alloc((size_t)(N + 1) * 4);
    int*   cursor   = (int*)  alloc((size_t)N * 4);
    int*   esorted  = (int*)  alloc((size_t)E * 4);
    f16*   xs       = (f16*)  alloc((size_t)N * 128 * 2);
    f16*   wt1      = (f16*)  alloc((size_t)256 * 128 * 2);  // [256][128]
    f16*   wt2      = (f16*)  alloc((size_t)128 * 256 * 2);  // [128][256]
    f16*   agg1     = (f16*)  alloc((size_t)N * 128 * 2);
    f16*   h1       = (f16*)  alloc((size_t)N * 256 * 2);
    f16*   tbuf     = (f16*)  alloc((size_t)N * 128 * 2);
    (void)ws_size; (void)n_in;

    float* out = (float*)d_out; (void)out_size;

    // --- CSR + degree scales ---
    hipMemsetAsync(cnt, 0, (size_t)N * sizeof(int), stream);
    count_kernel<<<2048, 256, 0, stream>>>(e_dst, cnt, E);
    scan1_kernel<<<NB, 256, 0, stream>>>(cnt, slocal, partials, disq, N);
    scan2_kernel<<<1, 1024, 0, stream>>>(partials, NB);
    scan3_kernel<<<NB, 256, 0, stream>>>(slocal, partials, row_ptr, cursor, N, E);
    csr_fill_kernel<<<2048, 256, 0, stream>>>(e_src, e_dst, cursor, esorted, E);

    // --- merged conversions (xs needs disq; weights independent) ---
    {
        long long n4 = (long long)N * 128 / 4;
        long long total = n4 + 32768 + 32768;
        cvt_all_kernel<<<(int)((total + 255) / 256), 256, 0, stream>>>(
            (const float4*)x, disq, xs, W1, wt1, W2, wt2, n4);
    }

    // --- layer 1: gather xs -> agg1 ; GEMM (+scale+bias+relu) -> h1 ---
    {
        long long waves = ((long long)N + 3) / 4;
        int blocks = (int)((waves + 3) / 4);
        gather_sum_f16_kernel<<<blocks, 256, 0, stream>>>(
            (const float4*)xs, (float4*)agg1, row_ptr, esorted, N);
    }
    {
        dim3 g(256 / 64, (N + 127) / 128);
        gemm_f16_kernel<1><<<g, 256, 0, stream>>>(agg1, wt1, h1, disq, b1,
                                                  N, 128, 256);
    }

    // --- layer 2: GEMM (+scale) -> tbuf ; gather + relu + FC -> out ---
    {
        dim3 g(128 / 64, (N + 127) / 128);
        gemm_f16_kernel<0><<<g, 256, 0, stream>>>(h1, wt2, tbuf, disq, nullptr,
                                                  N, 256, 128);
    }
    {
        long long waves = ((long long)N + 3) / 4;
        int blocks = (int)((waves + 3) / 4);
        gather_fc_kernel<<<blocks, 256, 0, stream>>>(
            (const float4*)tbuf, row_ptr, esorted, disq, b2, Wfc, bfc, out, N);
    }
}

// Round 9
// 229.051 us; speedup vs baseline: 12.3999x; 1.0253x over previous
//
#include <hip/hip_runtime.h>

// ---------------------------------------------------------------------------
// GCN 2-layer + FC head. f16 MFMA GEMMs, CSR gather, fp32 accumulation.
// Layer 1 aggregate-first:  A_hat(XW) = (A_hat X)W
//   xs   = f16(s.x)                     [N,128]
//   agg1 = xs[i] + sum_{j->i} xs[j]     (gather, 256B rows, x8 unrolled)
//   h1   = f16(relu(s.(agg1@W1) + b1))  (GEMM epilogue fused)   [N,256]
//   t    = f16(s.(h1@W2))               (GEMM epilogue)         [N,128]
//   out  = relu(s.(t[i]+sum t[j]) + b2) @ Wfc + bfc  (fused)    [N,6]
// GEMM: 128x128 tile, global_load_lds staging (source-swizzled), dbuf.
// Launch chain (10): memset, count+wtcvt, scan1, scan2, scan3+xscvt,
//                    csr_fill, gather1, gemm1, gemm2, gather_fc.
// ---------------------------------------------------------------------------

typedef _Float16 f16;
typedef __attribute__((ext_vector_type(8))) _Float16 f16x8;
typedef __attribute__((ext_vector_type(4))) float f32x4;

#define GLOAD16(g, l)                                                      \
    __builtin_amdgcn_global_load_lds(                                      \
        (const __attribute__((address_space(1))) void*)(g),                \
        (__attribute__((address_space(3))) void*)(l), 16, 0, 0)

// ---------------- fused: degree count + weight transpose-convert ----------
// blocks [0,128):   wt1[j], j = b*256+tid   (wt1[n][k] = f16 W1[k][n], 32768)
// blocks [128,256): wt2[j]                  (wt2[n][k] = f16 W2[k][n], 32768)
// blocks [256, 256+2048): grid-stride count of dst into cnt
__global__ void count_wt_kernel(const int* __restrict__ dst, int* __restrict__ cnt,
                                int e,
                                const float* __restrict__ W1, f16* __restrict__ wt1,
                                const float* __restrict__ W2, f16* __restrict__ wt2) {
    int b = blockIdx.x;
    if (b < 128) {
        int j = b * 256 + threadIdx.x;
        int nn = j >> 7, k = j & 127;
        wt1[j] = (f16)W1[(long long)k * 256 + nn];
    } else if (b < 256) {
        int j = (b - 128) * 256 + threadIdx.x;
        int nn = j >> 8, k = j & 255;
        wt2[j] = (f16)W2[(long long)k * 128 + nn];
    } else {
        for (int i = (b - 256) * 256 + (int)threadIdx.x; i < e; i += 2048 * 256)
            atomicAdd(&cnt[dst[i]], 1);
    }
}

// Phase 1: per-block (256 thr x 4) local exclusive scan + totals + disq.
__global__ void scan1_kernel(const int* __restrict__ cnt, int* __restrict__ local,
                             int* __restrict__ partials, float* __restrict__ disq,
                             int n) {
    __shared__ int lds[256];
    int base = blockIdx.x * 1024;
    int t = threadIdx.x;
    int v[4];
    int sum = 0;
    #pragma unroll
    for (int j = 0; j < 4; j++) {
        int i = base + t * 4 + j;
        v[j] = (i < n) ? cnt[i] : 0;
        if (i < n) disq[i] = rsqrtf(1.0f + (float)v[j]);
        sum += v[j];
    }
    lds[t] = sum;
    __syncthreads();
    for (int off = 1; off < 256; off <<= 1) {
        int x = (t >= off) ? lds[t - off] : 0;
        __syncthreads();
        lds[t] += x;
        __syncthreads();
    }
    int excl = lds[t] - sum;
    if (t == 255) partials[blockIdx.x] = lds[255];
    int run = excl;
    #pragma unroll
    for (int j = 0; j < 4; j++) {
        int i = base + t * 4 + j;
        if (i < n) local[i] = run;
        run += v[j];
    }
}

// Phase 2: single block scans block totals (nb <= 1024) -> exclusive.
__global__ void scan2_kernel(int* __restrict__ partials, int nb) {
    __shared__ int lds[1024];
    int t = threadIdx.x;
    int v = (t < nb) ? partials[t] : 0;
    lds[t] = v;
    __syncthreads();
    for (int off = 1; off < 1024; off <<= 1) {
        int x = (t >= off) ? lds[t - off] : 0;
        __syncthreads();
        lds[t] += x;
        __syncthreads();
    }
    if (t < nb) partials[t] = lds[t] - v;
}

// Phase 3 (+xs convert): blocks [0,nb): row_ptr/cursor; blocks [nb,..): xs.
__global__ void scan3_xs_kernel(const int* __restrict__ local,
                                const int* __restrict__ partials,
                                int* __restrict__ row_ptr, int* __restrict__ cursor,
                                int n, int e_total, int nb,
                                const float4* __restrict__ x,
                                const float* __restrict__ disq,
                                f16* __restrict__ xs, long long n4) {
    int b = blockIdx.x;
    int t = threadIdx.x;
    if (b < nb) {
        int base = b * 1024;
        int add = partials[b];
        #pragma unroll
        for (int j = 0; j < 4; j++) {
            int i = base + t * 4 + j;
            if (i < n) {
                int p = local[i] + add;
                row_ptr[i] = p;
                cursor[i] = p;
            }
        }
        if (b == 0 && t == 0) row_ptr[n] = e_total;
        return;
    }
    long long i = (long long)(b - nb) * 256 + t;
    if (i < n4) {
        float4 v = x[i];
        float s = disq[i >> 5];
        union { f16 h[4]; short4 s4; } u;
        u.h[0] = (f16)(v.x * s); u.h[1] = (f16)(v.y * s);
        u.h[2] = (f16)(v.z * s); u.h[3] = (f16)(v.w * s);
        *(short4*)(xs + i * 4) = u.s4;
    }
}

__global__ void csr_fill_kernel(const int* __restrict__ src, const int* __restrict__ dst,
                                int* __restrict__ cursor, int* __restrict__ esorted,
                                int e) {
    for (int i = blockIdx.x * blockDim.x + threadIdx.x; i < e;
         i += gridDim.x * blockDim.x) {
        int d = dst[i];
        int pos = atomicAdd(&cursor[d], 1);
        esorted[pos] = src[i];
    }
}

// ---------------- f16 MFMA GEMM: 128x128 tile, BK=64, dbuf gload_lds ------
// C[M][Nc] = f16( epilogue( A[M][K] @ Bt[Nc][K]^T ) )
// MODE 0: *rowscale            MODE 1: relu(*rowscale + bias[col])
// 4 waves (2x2); wave = 64 rows x 64 cols = 4x4 frags of 16x16x32.
// LDS row = 64 f16 = 128B; 16B chunk g at byte (g*16)^((r&7)<<4).
// Staging: LINEAR LDS dest + inverse-swizzled per-lane GLOBAL source (G21).
template <int MODE>
__global__ __launch_bounds__(256)
void gemm_f16_kernel(const f16* __restrict__ A,
                     const f16* __restrict__ Bt,
                     f16* __restrict__ C,
                     const float* __restrict__ rowscale,
                     const float* __restrict__ bias,
                     int M, int K, int Nc) {
    __shared__ __align__(16) char smem[2 * 32 * 1024];   // 2 x (16KB A + 16KB B)
    const int tid = threadIdx.x;
    const int lane = tid & 63;
    const int wid = tid >> 6;
    const int wr = wid >> 1;      // 0..1 -> 64-row half
    const int wc = wid & 1;       // 0..1 -> 64-col half
    const int row0 = blockIdx.y * 128;
    const int col0 = blockIdx.x * 128;
    const bool rows_full = (row0 + 128 <= M);

    f32x4 acc[4][4];
    #pragma unroll
    for (int mr = 0; mr < 4; mr++)
        #pragma unroll
        for (int nr = 0; nr < 4; nr++)
            acc[mr][nr] = (f32x4){0.f, 0.f, 0.f, 0.f};

    auto stage = [&](int buf, int k0) {
        char* as = smem + buf * (32 * 1024);
        char* bs = as + 16 * 1024;
        if (rows_full) {
            #pragma unroll
            for (int i = 0; i < 4; i++) {
                int flat = i * 256 + tid;            // 0..1023 A chunks
                int r = flat >> 3, gp = flat & 7;
                int g = gp ^ (r & 7);                // inverse-swizzled source
                const f16* src = A + (long long)(row0 + r) * K + k0 + g * 8;
                GLOAD16(src, as + (i * 256 + wid * 64) * 16);
            }
        } else {
            #pragma unroll
            for (int i = 0; i < 4; i++) {
                int flat = i * 256 + tid;
                int r = flat >> 3, gp = flat & 7;
                int g = gp ^ (r & 7);
                int gr = row0 + r;
                float4 v = {0.f, 0.f, 0.f, 0.f};
                if (gr < M) v = *(const float4*)(A + (long long)gr * K + k0 + g * 8);
                *(float4*)(as + flat * 16) = v;      // same linear layout
            }
        }
        #pragma unroll
        for (int i = 0; i < 4; i++) {
            int flat = i * 256 + tid;                // 0..1023 B chunks
            int nn = flat >> 3, gp = flat & 7;
            int g = gp ^ (nn & 7);
            const f16* src = Bt + (long long)(col0 + nn) * K + k0 + g * 8;
            GLOAD16(src, bs + (i * 256 + wid * 64) * 16);
        }
    };

    auto compute = [&](int buf) {
        char* as = smem + buf * (32 * 1024);
        char* bs = as + 16 * 1024;
        #pragma unroll
        for (int ks = 0; ks < 2; ks++) {
            const int kb = (ks * 32 + ((lane >> 4) * 8)) * 2;
            f16x8 af[4], bf[4];
            #pragma unroll
            for (int mr = 0; mr < 4; mr++) {
                int r = wr * 64 + mr * 16 + (lane & 15);
                af[mr] = *(const f16x8*)(as + r * 128 + (kb ^ ((r & 7) << 4)));
            }
            #pragma unroll
            for (int nr = 0; nr < 4; nr++) {
                int c = wc * 64 + nr * 16 + (lane & 15);
                bf[nr] = *(const f16x8*)(bs + c * 128 + (kb ^ ((c & 7) << 4)));
            }
            #pragma unroll
            for (int mr = 0; mr < 4; mr++)
                #pragma unroll
                for (int nr = 0; nr < 4; nr++)
                    acc[mr][nr] = __builtin_amdgcn_mfma_f32_16x16x32_f16(
                        af[mr], bf[nr], acc[mr][nr], 0, 0, 0);
        }
    };

    const int nt = K >> 6;
    stage(0, 0);
    __syncthreads();
    int cur = 0;
    for (int t = 0; t < nt; t++) {
        if (t + 1 < nt) stage(cur ^ 1, (t + 1) * 64);
        compute(cur);
        __syncthreads();
        cur ^= 1;
    }

    // epilogue: C/D map col=lane&15, row=(lane>>4)*4+reg  [m89-verified]
    float bv[4] = {0.f, 0.f, 0.f, 0.f};
    if (MODE == 1) {
        #pragma unroll
        for (int nr = 0; nr < 4; nr++)
            bv[nr] = bias[col0 + wc * 64 + nr * 16 + (lane & 15)];
    }
    #pragma unroll
    for (int mr = 0; mr < 4; mr++) {
        #pragma unroll
        for (int reg = 0; reg < 4; reg++) {
            int row = row0 + wr * 64 + mr * 16 + (lane >> 4) * 4 + reg;
            if (row < M) {
                float s = rowscale[row];
                int col = col0 + wc * 64 + (lane & 15);
                #pragma unroll
                for (int nr = 0; nr < 4; nr++) {
                    float v = acc[mr][nr][reg] * s;
                    if (MODE == 1) v = fmaxf(v + bv[nr], 0.0f);
                    C[(long long)row * Nc + col + nr * 16] = (f16)v;
                }
            }
        }
    }
}

// ---------------- gather (pure sum, 128-ch f16 rows, x8 unrolled) --------
__global__ void gather_sum_f16_kernel(const float4* __restrict__ h,
                                      float4* __restrict__ out,
                                      const int* __restrict__ row_ptr,
                                      const int* __restrict__ esorted, int n) {
    int lane = threadIdx.x & 63;
    long long wave = (blockIdx.x * (long long)blockDim.x + threadIdx.x) >> 6;
    int sub = lane >> 4;            // 4 nodes/wave
    int sl = lane & 15;
    long long node = wave * 4 + sub;
    if (node >= n) return;
    int beg = row_ptr[node], end = row_ptr[node + 1];
    float acc[8];
    {
        float4 v = h[node * 16 + sl];
        const f16* hp = (const f16*)&v;
        #pragma unroll
        for (int j = 0; j < 8; j++) acc[j] = (float)hp[j];
    }
    int e = beg;
    for (; e + 8 <= end; e += 8) {  // 8 independent row loads in flight
        int s[8];
        #pragma unroll
        for (int u = 0; u < 8; u++) s[u] = esorted[e + u];
        float4 v[8];
        #pragma unroll
        for (int u = 0; u < 8; u++) v[u] = h[(long long)s[u] * 16 + sl];
        #pragma unroll
        for (int u = 0; u < 8; u++) {
            const f16* p = (const f16*)&v[u];
            #pragma unroll
            for (int j = 0; j < 8; j++) acc[j] += (float)p[j];
        }
    }
    for (; e < end; e++) {
        int s = esorted[e];
        float4 v = h[(long long)s * 16 + sl];
        const f16* hp = (const f16*)&v;
        #pragma unroll
        for (int j = 0; j < 8; j++) acc[j] += (float)hp[j];
    }
    union { float4 f4; f16 hh[8]; } o;
    #pragma unroll
    for (int j = 0; j < 8; j++) o.hh[j] = (f16)acc[j];
    out[node * 16 + sl] = o.f4;
}

// ---------------- gather2 + relu + FC head (x8 unrolled) -----------------
// h2 = relu(disq[node]*(t[node]+sum t[src]) + b2);  out = h2 @ Wfc + bfc
__global__ void gather_fc_kernel(const float4* __restrict__ t,
                                 const int* __restrict__ row_ptr,
                                 const int* __restrict__ esorted,
                                 const float* __restrict__ disq,
                                 const float* __restrict__ b2,
                                 const float* __restrict__ Wfc,   // [128][6]
                                 const float* __restrict__ bfc,   // [6]
                                 float* __restrict__ out, int n) {
    __shared__ float wf[6 * 132];    // transposed [6][128], padded row 132
    for (int i = threadIdx.x; i < 6 * 128; i += 256) {
        int k = i >> 7, ch = i & 127;
        wf[k * 132 + ch] = Wfc[ch * 6 + k];
    }
    __syncthreads();
    int lane = threadIdx.x & 63;
    long long wave = (blockIdx.x * (long long)blockDim.x + threadIdx.x) >> 6;
    int sub = lane >> 4;
    int sl = lane & 15;
    long long node = wave * 4 + sub;
    if (node >= n) return;
    int beg = row_ptr[node], end = row_ptr[node + 1];
    float acc[8];
    {
        float4 v = t[node * 16 + sl];
        const f16* hp = (const f16*)&v;
        #pragma unroll
        for (int j = 0; j < 8; j++) acc[j] = (float)hp[j];
    }
    int e = beg;
    for (; e + 8 <= end; e += 8) {
        int s[8];
        #pragma unroll
        for (int u = 0; u < 8; u++) s[u] = esorted[e + u];
        float4 v[8];
        #pragma unroll
        for (int u = 0; u < 8; u++) v[u] = t[(long long)s[u] * 16 + sl];
        #pragma unroll
        for (int u = 0; u < 8; u++) {
            const f16* p = (const f16*)&v[u];
            #pragma unroll
            for (int j = 0; j < 8; j++) acc[j] += (float)p[j];
        }
    }
    for (; e < end; e++) {
        int s = esorted[e];
        float4 v = t[(long long)s * 16 + sl];
        const f16* hp = (const f16*)&v;
        #pragma unroll
        for (int j = 0; j < 8; j++) acc[j] += (float)hp[j];
    }
    float sc = disq[node];
    const float4* b4 = (const float4*)(b2 + sl * 8);
    float4 bb0 = b4[0], bb1 = b4[1];
    float bb[8] = {bb0.x, bb0.y, bb0.z, bb0.w, bb1.x, bb1.y, bb1.z, bb1.w};
    float h2[8];
    #pragma unroll
    for (int j = 0; j < 8; j++)
        h2[j] = fmaxf(fmaf(acc[j], sc, bb[j]), 0.0f);
    float p[6];
    #pragma unroll
    for (int k = 0; k < 6; k++) {
        float s = 0.f;
        #pragma unroll
        for (int j = 0; j < 8; j++) s += h2[j] * wf[k * 132 + sl * 8 + j];
        p[k] = s;
    }
    #pragma unroll
    for (int off = 8; off >= 1; off >>= 1)
        #pragma unroll
        for (int k = 0; k < 6; k++) p[k] += __shfl_down(p[k], off);
    if (sl == 0) {
        #pragma unroll
        for (int k = 0; k < 6; k++)
            out[(long long)node * 6 + k] = p[k] + bfc[k];
    }
}

extern "C" void kernel_launch(void* const* d_in, const int* in_sizes, int n_in,
                              void* d_out, int out_size, void* d_ws, size_t ws_size,
                              hipStream_t stream) {
    const float* x   = (const float*)d_in[0];
    const float* W1  = (const float*)d_in[1];
    const float* b1  = (const float*)d_in[2];
    const float* W2  = (const float*)d_in[3];
    const float* b2  = (const float*)d_in[4];
    const float* Wfc = (const float*)d_in[5];
    const float* bfc = (const float*)d_in[6];
    const int* edges = (const int*)d_in[7];

    const int N = in_sizes[0] / 128;       // 50000
    const int E = in_sizes[7] / 2;         // 500000
    const int* e_src = edges;
    const int* e_dst = edges + E;

    char* ws = (char*)d_ws;
    size_t off = 0;
    auto alloc = [&](size_t bytes) {
        void* p = ws + off;
        off += (bytes + 255) & ~(size_t)255;
        return p;
    };
    const int NB = (N + 1023) / 1024;
    float* disq     = (float*)alloc((size_t)N * 4);
    int*   cnt      = (int*)  alloc((size_t)N * 4);
    int*   slocal   = (int*)  alloc((size_t)N * 4);
    int*   partials = (int*)  alloc((size_t)NB * 4);
    int*   row_ptr  = (int*)  alloc((size_t)(N + 1) * 4);
    int*   cursor   = (int*)  alloc((size_t)N * 4);
    int*   esorted  = (int*)  alloc((size_t)E * 4);
    f16*   xs       = (f16*)  alloc((size_t)N * 128 * 2);
    f16*   wt1      = (f16*)  alloc((size_t)256 * 128 * 2);  // [256][128]
    f16*   wt2      = (f16*)  alloc((size_t)128 * 256 * 2);  // [128][256]
    f16*   agg1     = (f16*)  alloc((size_t)N * 128 * 2);
    f16*   h1       = (f16*)  alloc((size_t)N * 256 * 2);
    f16*   tbuf     = (f16*)  alloc((size_t)N * 128 * 2);
    (void)ws_size; (void)n_in;

    float* out = (float*)d_out; (void)out_size;

    // --- CSR + degree scales + conversions (fused into chain) ---
    hipMemsetAsync(cnt, 0, (size_t)N * sizeof(int), stream);
    count_wt_kernel<<<256 + 2048, 256, 0, stream>>>(e_dst, cnt, E,
                                                    W1, wt1, W2, wt2);
    scan1_kernel<<<NB, 256, 0, stream>>>(cnt, slocal, partials, disq, N);
    scan2_kernel<<<1, 1024, 0, stream>>>(partials, NB);
    {
        long long n4 = (long long)N * 128 / 4;
        int xb = (int)((n4 + 255) / 256);
        scan3_xs_kernel<<<NB + xb, 256, 0, stream>>>(
            slocal, partials, row_ptr, cursor, N, E, NB,
            (const float4*)x, disq, xs, n4);
    }
    csr_fill_kernel<<<2048, 256, 0, stream>>>(e_src, e_dst, cursor, esorted, E);

    // --- layer 1: gather xs -> agg1 ; GEMM (+scale+bias+relu) -> h1 ---
    {
        long long waves = ((long long)N + 3) / 4;
        int blocks = (int)((waves + 3) / 4);
        gather_sum_f16_kernel<<<blocks, 256, 0, stream>>>(
            (const float4*)xs, (float4*)agg1, row_ptr, esorted, N);
    }
    {
        dim3 g(256 / 128, (N + 127) / 128);
        gemm_f16_kernel<1><<<g, 256, 0, stream>>>(agg1, wt1, h1, disq, b1,
                                                  N, 128, 256);
    }

    // --- layer 2: GEMM (+scale) -> tbuf ; gather + relu + FC -> out ---
    {
        dim3 g(128 / 128, (N + 127) / 128);
        gemm_f16_kernel<0><<<g, 256, 0, stream>>>(h1, wt2, tbuf, disq, nullptr,
                                                  N, 256, 128);
    }
    {
        long long waves = ((long long)N + 3) / 4;
        int blocks = (int)((waves + 3) / 4);
        gather_fc_kernel<<<blocks, 256, 0, stream>>>(
            (const float4*)tbuf, row_ptr, esorted, disq, b2, Wfc, bfc, out, N);
    }
}